// Round 8
// baseline (1316.364 us; speedup 1.0000x reference)
//
#include <hip/hip_runtime.h>
#include <math.h>

// ---------------------------------------------------------------------------
// TemporalUnitRolloutV341 — GRU rollout, 32 steps over 2048 rows of D=512.
// R8: R7 pipeline (1 dispatch/step: gru(t) || ln(t-1) || sem(t-2), bf16x3
// recurrence GEMMs) + LN1 stats rebuilt: block-local TWO-PASS fp32 (no
// atomics, no E[x2]-m2 cancellation). Low-variance rows amplify stat errors
// by rsd~300 into the dyn outlier — this was the 0.156 absmax in R5-R7, and
// the fp32-atomic ordering was the R5 replay drift.
// ---------------------------------------------------------------------------

typedef unsigned short u16;
using bf16x8 = __attribute__((ext_vector_type(8))) short;
using f32x4  = __attribute__((ext_vector_type(4))) float;
using f4     = __attribute__((ext_vector_type(4))) float;

#define DEV __device__ __forceinline__

constexpr int D   = 512;
constexpr int D3  = 1536;
constexpr int H   = 32;
constexpr int BU  = 2048;
constexpr long long OUT_HALF = (long long)BU * H * D;

DEV u16 f2bf(float x){
  union { float f; unsigned u; } c; c.f = x;
  unsigned u = c.u;
  u += 0x7fffu + ((u >> 16) & 1u);
  return (u16)(u >> 16);
}
DEV float bf2f(u16 b){
  union { unsigned u; float f; } c; c.u = ((unsigned)b) << 16; return c.f;
}

DEV void gload_lds16(const void* g, void* l){
  __builtin_amdgcn_global_load_lds(
      (const __attribute__((address_space(1))) void*)g,
      (__attribute__((address_space(3))) void*)l, 16, 0, 0);
}

DEV f32x4 mfma16(bf16x8 a, bf16x8 b, f32x4 c){
  return __builtin_amdgcn_mfma_f32_16x16x32_bf16(a, b, c, 0, 0, 0);
}

DEV float sigm(float x){ return 1.f / (1.f + expf(-x)); }

struct SP {
  u16 *hbh0, *hbh1, *hbl0, *hbl1, *hid0, *hid1;
  float *h0, *h1, *dyn, *sems;
  const u16 *whh_hi, *whh_lo, *W1h, *w2;
  const float *G0, *Tg, *bhh, *ln_g, *ln_b, *Ssem, *Ssem2, *Psem, *c1, *c2p,
              *zsem, *b2;
};

// ---------------------------------------------------------------------------
// Setup: hi/lo splits, folded matrices, c1/c2p, Tg.
// ---------------------------------------------------------------------------
__global__ __launch_bounds__(256) void prep_kernel(
    const float* __restrict__ z_dyn, const float* __restrict__ z_sem,
    const float* __restrict__ te_w,  const float* __restrict__ w_ih,
    const float* __restrict__ w_hh,  const float* __restrict__ ln2_g,
    const float* __restrict__ ln2_b, const float* __restrict__ w1,
    const float* __restrict__ b1,    const float* __restrict__ w2,
    float* __restrict__ h1, u16* __restrict__ hbh1, u16* __restrict__ hbl1,
    u16* __restrict__ sem_hi, u16* __restrict__ sem_lo,
    u16* __restrict__ wih_hi, u16* __restrict__ wih_lo,
    u16* __restrict__ whh_hi, u16* __restrict__ whh_lo,
    u16* __restrict__ W1s, u16* __restrict__ W1h, u16* __restrict__ w2bf,
    float* __restrict__ c1, float* __restrict__ c2p, float* __restrict__ Tg)
{
  int i = blockIdx.x * 256 + threadIdx.x;
  if (i < BU * D) {
    float hv = z_dyn[i];
    h1[i] = hv;
    u16 hh = f2bf(hv);
    hbh1[i] = hh;
    hbl1[i] = f2bf(hv - bf2f(hh));
    float sv = z_sem[i];
    u16 sh_ = f2bf(sv);
    sem_hi[i] = sh_;
    sem_lo[i] = f2bf(sv - bf2f(sh_));
  }
  if (i < D3 * D) {
    float wv = w_ih[i];
    u16 wh = f2bf(wv);
    wih_hi[i] = wh;
    wih_lo[i] = f2bf(wv - bf2f(wh));
    float uv = w_hh[i];
    u16 uh = f2bf(uv);
    whh_hi[i] = uh;
    whh_lo[i] = f2bf(uv - bf2f(uh));
  }
  if (i < D * D) {
    int k = i >> 9, j = i & 511;
    W1s[i]  = f2bf(w1[k * 1024 + j] * ln2_g[j]);
    W1h[i]  = f2bf(w1[k * 1024 + 512 + j] * ln2_g[512 + j]);
    w2bf[i] = f2bf(w2[i]);
  }
  if (i < D) {
    float s1 = 0.f, s2 = 0.f;
    for (int j = 0; j < 1024; ++j) {
      float w = w1[i * 1024 + j];
      s1 += w * ln2_g[j];
      s2 += w * ln2_b[j];
    }
    c1[i] = s1;
    c2p[i] = s2 + b1[i];
  }
  if (i < H * D3) {
    int t = i / D3, c = i % D3;
    float s = 0.f;
    for (int d0 = 0; d0 < D; ++d0) s += te_w[t * D + d0] * w_ih[c * D + d0];
    Tg[i] = s;
  }
}

// Per-row sums of sem and sem^2 (ln2 stats split). One wave per row.
__global__ __launch_bounds__(256) void rowstats_kernel(
    const float* __restrict__ sem, float* __restrict__ Ssem,
    float* __restrict__ Ssem2)
{
  const int wid = threadIdx.x >> 6, lane = threadIdx.x & 63;
  const int row = blockIdx.x * 4 + wid;
  const float* p = sem + (size_t)row * D + lane * 8;
  float4 a0 = *(const float4*)p;
  float4 a1 = *(const float4*)(p + 4);
  float s  = a0.x + a0.y + a0.z + a0.w + a1.x + a1.y + a1.z + a1.w;
  float s2 = a0.x*a0.x + a0.y*a0.y + a0.z*a0.z + a0.w*a0.w
           + a1.x*a1.x + a1.y*a1.y + a1.z*a1.z + a1.w*a1.w;
  #pragma unroll
  for (int o = 1; o < 64; o <<= 1) { s += __shfl_xor(s, o); s2 += __shfl_xor(s2, o); }
  if (lane == 0) { Ssem[row] = s; Ssem2[row] = s2; }
}

// ---------------------------------------------------------------------------
// Setup GEMMs: grid (32, 32). by<24 -> G0 tile (bf16x3, +b_ih);
// by>=24 -> Psem tile (plain bf16). 64x64 NT, single-buffered 32KB LDS.
// ---------------------------------------------------------------------------
__global__ __launch_bounds__(256) void setup_kernel(
    const u16* __restrict__ sem_hi, const u16* __restrict__ sem_lo,
    const u16* __restrict__ wih_hi, const u16* __restrict__ wih_lo,
    const u16* __restrict__ W1s, float* __restrict__ G0,
    float* __restrict__ Psem, const float* __restrict__ b_ih)
{
  __shared__ __align__(16) char smem[32768];
  char* Ah = smem;
  char* Al = smem + 8192;
  char* Bh = smem + 16384;
  char* Bl = smem + 24576;
  const int tid = threadIdx.x, wid = tid >> 6, lane = tid & 63;
  const int wr = wid >> 1, wc = wid & 1;
  const bool isG0 = blockIdx.y < 24;
  const u16* Bsrc = isG0 ? wih_hi : W1s;
  const int row0 = blockIdx.x * 64;
  const int col0 = (isG0 ? blockIdx.y : blockIdx.y - 24) * 64;

  f32x4 acc[2][2] = {};
  for (int kt = 0; kt < 8; ++kt) {
    #pragma unroll
    for (int it = 0; it < 2; ++it) {
      int s = it * 256 + tid, pr = s >> 3, pc = s & 7;
      int lch = pc ^ (pr & 7);
      size_t aoff = (size_t)(row0 + pr) * D + kt * 64 + lch * 8;
      size_t boff = (size_t)(col0 + pr) * D + kt * 64 + lch * 8;
      gload_lds16(sem_hi + aoff, Ah + it * 4096 + wid * 1024);
      gload_lds16(Bsrc + boff,   Bh + it * 4096 + wid * 1024);
      if (isG0) {
        gload_lds16(sem_lo + aoff, Al + it * 4096 + wid * 1024);
        gload_lds16(wih_lo + boff, Bl + it * 4096 + wid * 1024);
      }
    }
    asm volatile("s_waitcnt vmcnt(0)" ::: "memory");
    __syncthreads();

    const int lc = lane & 15, hi2 = lane >> 4;
    #pragma unroll
    for (int kk = 0; kk < 2; ++kk) {
      int ch = kk * 4 + hi2;
      bf16x8 afh[2], afl[2], bfh[2], bfl[2];
      #pragma unroll
      for (int mi = 0; mi < 2; ++mi) {
        int r = wr * 32 + mi * 16 + lc;
        int o = r * 128 + ((ch ^ (r & 7)) << 4);
        afh[mi] = *(const bf16x8*)(Ah + o);
        if (isG0) afl[mi] = *(const bf16x8*)(Al + o);
      }
      #pragma unroll
      for (int ci = 0; ci < 2; ++ci) {
        int r = wc * 32 + ci * 16 + lc;
        int o = r * 128 + ((ch ^ (r & 7)) << 4);
        bfh[ci] = *(const bf16x8*)(Bh + o);
        if (isG0) bfl[ci] = *(const bf16x8*)(Bl + o);
      }
      #pragma unroll
      for (int mi = 0; mi < 2; ++mi)
        #pragma unroll
        for (int ci = 0; ci < 2; ++ci) {
          f32x4 a = acc[mi][ci];
          a = mfma16(afh[mi], bfh[ci], a);
          if (isG0) {
            a = mfma16(afl[mi], bfh[ci], a);
            a = mfma16(afh[mi], bfl[ci], a);
          }
          acc[mi][ci] = a;
        }
    }
    __syncthreads();
  }
  const int lj = lane >> 4, lc2 = lane & 15;
  #pragma unroll
  for (int mi = 0; mi < 2; ++mi)
    #pragma unroll
    for (int ci = 0; ci < 2; ++ci)
      #pragma unroll
      for (int j = 0; j < 4; ++j) {
        int row = row0 + wr * 32 + mi * 16 + lj * 4 + j;
        int col = col0 + wc * 32 + ci * 16 + lc2;
        float v = acc[mi][ci][j];
        if (isG0) G0[(size_t)row * D3 + col] = v + b_ih[col];
        else      Psem[(size_t)row * D + col] = v;
      }
}

// ---------------------------------------------------------------------------
// Pipelined step kernel: grid (64, 8), one dispatch per t in [0, 34).
//   phase 1: gru(t)   (t < 32)  bf16x3 gh GEMM, no atomics
//   phase 2: ln(t-1)  (1<=t<=32) two-pass block-local LN1 stats + hid GEMM
//   phase 3: sem(t-2) (t >= 2)  out_sems GEMM
// ---------------------------------------------------------------------------
__global__ __launch_bounds__(256) void step_kernel(SP p, int t){
  __shared__ __align__(16) char smem[57344];
  const int tid = threadIdx.x, wid = tid >> 6, lane = tid & 63;
  const int wr = wid >> 1, wc = wid & 1;
  const int lc = lane & 15, hi2 = lane >> 4;
  const int lj = lane >> 4, lc2 = lane & 15;

  // ---------------- phase 1: gru(t), bf16x3 ----------------
  if (t < H) {
    const u16* hih = (t & 1) ? p.hbh0 : p.hbh1;
    const u16* hil = (t & 1) ? p.hbl0 : p.hbl1;
    u16* hoh      = (t & 1) ? p.hbh1 : p.hbh0;
    u16* hol      = (t & 1) ? p.hbl1 : p.hbl0;
    const float* h_in = (t & 1) ? p.h0 : p.h1;
    float* h_out      = (t & 1) ? p.h1 : p.h0;
    const int row0 = blockIdx.x * 32, c0 = blockIdx.y * 64;
    char* Ah = smem;            // 4KB
    char* Al = smem + 4096;     // 4KB
    char* Bh = smem + 8192;     // 24KB
    char* Bl = smem + 32768;    // 24KB
    f32x4 acc[6] = {};

    for (int kt = 0; kt < 8; ++kt) {
      { int pr = tid >> 3, pc = tid & 7, lch = pc ^ (pr & 7);
        size_t off = (size_t)(row0 + pr) * D + kt * 64 + lch * 8;
        gload_lds16(hih + off, Ah + wid * 1024);
        gload_lds16(hil + off, Al + wid * 1024); }
      #pragma unroll
      for (int it = 0; it < 6; ++it) {
        int s = it * 256 + tid, pr = s >> 3, pc = s & 7;
        int lch = pc ^ (pr & 7);
        int g = pr >> 6, lr = pr & 63;
        size_t off = (size_t)(g * D + c0 + lr) * D + kt * 64 + lch * 8;
        gload_lds16(p.whh_hi + off, Bh + it * 4096 + wid * 1024);
        gload_lds16(p.whh_lo + off, Bl + it * 4096 + wid * 1024);
      }
      asm volatile("s_waitcnt vmcnt(0)" ::: "memory");
      __syncthreads();

      #pragma unroll
      for (int kk = 0; kk < 2; ++kk) {
        int ch = kk * 4 + hi2;
        int ra = wr * 16 + lc;
        int ao = ra * 128 + ((ch ^ (ra & 7)) << 4);
        bf16x8 afh = *(const bf16x8*)(Ah + ao);
        bf16x8 afl = *(const bf16x8*)(Al + ao);
        #pragma unroll
        for (int g = 0; g < 3; ++g)
          #pragma unroll
          for (int ci = 0; ci < 2; ++ci) {
            int rb = g * 64 + wc * 32 + ci * 16 + lc;
            int bo = rb * 128 + ((ch ^ (rb & 7)) << 4);
            bf16x8 bh = *(const bf16x8*)(Bh + bo);
            bf16x8 bl = *(const bf16x8*)(Bl + bo);
            f32x4 a = acc[g * 2 + ci];
            a = mfma16(afh, bh, a);
            a = mfma16(afl, bh, a);
            a = mfma16(afh, bl, a);
            acc[g * 2 + ci] = a;
          }
      }
      __syncthreads();
    }

    #pragma unroll
    for (int j = 0; j < 4; ++j) {
      int row = row0 + wr * 16 + lj * 4 + j;
      #pragma unroll
      for (int ci = 0; ci < 2; ++ci) {
        int col = c0 + wc * 32 + ci * 16 + lc2;
        float ar = acc[ci][j], az = acc[2 + ci][j], an = acc[4 + ci][j];
        size_t g0i = (size_t)row * D3 + col;
        float gr = p.G0[g0i]        + p.Tg[t * D3 + col];
        float gz = p.G0[g0i + 512]  + p.Tg[t * D3 + 512 + col];
        float gn = p.G0[g0i + 1024] + p.Tg[t * D3 + 1024 + col];
        float r = sigm(gr + ar + p.bhh[col]);
        float z = sigm(gz + az + p.bhh[512 + col]);
        float n = tanhf(gn + r * (an + p.bhh[1024 + col]));
        size_t hi_ = (size_t)row * D + col;
        float hnew = (1.f - z) * n + z * h_in[hi_];
        h_out[hi_] = hnew;
        u16 hh = f2bf(hnew);
        hoh[hi_] = hh;
        hol[hi_] = f2bf(hnew - bf2f(hh));
      }
    }
  }
  __syncthreads();

  // ---------------- phase 2: ln(t-1), two-pass stats ----------------
  if (t >= 1 && t <= H) {
    const int tt = t - 1;
    const float* hS = (tt & 1) ? p.h1 : p.h0;
    u16* hidW       = (tt & 1) ? p.hid1 : p.hid0;
    constexpr int BUFB = 12288;
    float* stm = (float*)(smem + 49152);
    float* str = stm + 32;
    const int row0 = blockIdx.x * 32, col0 = blockIdx.y * 64;
    const int rs = tid >> 3, qc = tid & 7;
    const int grow = row0 + rs;
    const float* hrow = hS + (size_t)grow * D;

    // pass A: mean (block-local, deterministic)
    float s1 = 0.f;
    #pragma unroll
    for (int kt = 0; kt < 8; ++kt) {
      const float* hp = hrow + kt * 64 + qc * 8;
      float4 a0 = *(const float4*)hp, a1 = *(const float4*)(hp + 4);
      s1 += ((a0.x + a0.y) + (a0.z + a0.w)) + ((a1.x + a1.y) + (a1.z + a1.w));
    }
    s1 += __shfl_xor(s1, 1); s1 += __shfl_xor(s1, 2); s1 += __shfl_xor(s1, 4);
    float m1 = s1 * (1.f / 512.f);
    // pass B: variance = mean((x-m)^2), ref-matched two-pass form
    float s2 = 0.f;
    #pragma unroll
    for (int kt = 0; kt < 8; ++kt) {
      const float* hp = hrow + kt * 64 + qc * 8;
      float4 a0 = *(const float4*)hp, a1 = *(const float4*)(hp + 4);
      float d0 = a0.x - m1, d1 = a0.y - m1, d2 = a0.z - m1, d3 = a0.w - m1;
      float d4 = a1.x - m1, d5 = a1.y - m1, d6 = a1.z - m1, d7 = a1.w - m1;
      s2 += ((d0*d0 + d1*d1) + (d2*d2 + d3*d3))
          + ((d4*d4 + d5*d5) + (d6*d6 + d7*d7));
    }
    s2 += __shfl_xor(s2, 1); s2 += __shfl_xor(s2, 2); s2 += __shfl_xor(s2, 4);
    float rsd1 = rsqrtf(s2 * (1.f / 512.f) + 1e-5f);

    float sh = 0.f, sh2 = 0.f;
    float hreg[8];

    auto loadA = [&](int kt){
      const float* hp = hrow + kt * 64 + qc * 8;
      float4 a0 = *(const float4*)hp, a1 = *(const float4*)(hp + 4);
      hreg[0]=a0.x; hreg[1]=a0.y; hreg[2]=a0.z; hreg[3]=a0.w;
      hreg[4]=a1.x; hreg[5]=a1.y; hreg[6]=a1.z; hreg[7]=a1.w;
    };
    auto procA = [&](int b, int kt){
      int cb = kt * 64 + qc * 8;
      float4 g0 = *(const float4*)(p.ln_g + cb), g1 = *(const float4*)(p.ln_g + cb + 4);
      float4 b0 = *(const float4*)(p.ln_b + cb), b1v = *(const float4*)(p.ln_b + cb + 4);
      float gg[8] = {g0.x,g0.y,g0.z,g0.w,g1.x,g1.y,g1.z,g1.w};
      float bb[8] = {b0.x,b0.y,b0.z,b0.w,b1v.x,b1v.y,b1v.z,b1v.w};
      float hn[8];
      #pragma unroll
      for (int k = 0; k < 8; ++k) {
        float x = (hreg[k] - m1) * rsd1 * gg[k] + bb[k];
        hn[k] = x; sh += x; sh2 += x * x;
      }
      if (blockIdx.y == 0) {
        float* dp = p.dyn + ((size_t)grow * H + tt) * D + cb;
        f4 v0 = {hn[0], hn[1], hn[2], hn[3]};
        f4 v1_ = {hn[4], hn[5], hn[6], hn[7]};
        __builtin_nontemporal_store(v0, (f4*)dp);
        __builtin_nontemporal_store(v1_, (f4*)(dp + 4));
      }
      union { u16 us[8]; uint4 u; } pk;
      #pragma unroll
      for (int k = 0; k < 8; ++k) pk.us[k] = f2bf(hn[k]);
      *(uint4*)(smem + b * BUFB + rs * 128 + ((qc ^ (rs & 7)) << 4)) = pk.u;
    };
    auto stageB = [&](int b, int kt){
      char* Bs = smem + b * BUFB + 4096;
      #pragma unroll
      for (int it = 0; it < 2; ++it) {
        int s = it * 256 + tid, pr = s >> 3, pcc = s & 7;
        int lch = pcc ^ (pr & 7);
        gload_lds16(p.W1h + (size_t)(col0 + pr) * D + kt * 64 + lch * 8,
                    Bs + it * 4096 + wid * 1024);
      }
    };

    stageB(0, 0); loadA(0); procA(0, 0);
    __syncthreads();
    int buf = 0;
    f32x4 acc2[2] = {};
    for (int kt = 0; kt < 8; ++kt) {
      if (kt < 7) { stageB(buf ^ 1, kt + 1); loadA(kt + 1); }
      const char* As = smem + buf * BUFB;
      const char* Bs = As + 4096;
      #pragma unroll
      for (int kk = 0; kk < 2; ++kk) {
        int ch = kk * 4 + hi2;
        int ra = wr * 16 + lc;
        bf16x8 af = *(const bf16x8*)(As + ra * 128 + ((ch ^ (ra & 7)) << 4));
        #pragma unroll
        for (int ci = 0; ci < 2; ++ci) {
          int rb = wc * 32 + ci * 16 + lc;
          bf16x8 bb = *(const bf16x8*)(Bs + rb * 128 + ((ch ^ (rb & 7)) << 4));
          acc2[ci] = mfma16(af, bb, acc2[ci]);
        }
      }
      if (kt < 7) procA(buf ^ 1, kt + 1);
      __syncthreads();
      buf ^= 1;
    }

    sh  += __shfl_xor(sh, 1);  sh  += __shfl_xor(sh, 2);  sh  += __shfl_xor(sh, 4);
    sh2 += __shfl_xor(sh2, 1); sh2 += __shfl_xor(sh2, 2); sh2 += __shfl_xor(sh2, 4);
    if (qc == 0) {
      float m2 = (p.Ssem[grow] + sh) * (1.f / 1024.f);
      float vv = (p.Ssem2[grow] + sh2) * (1.f / 1024.f) - m2 * m2;
      stm[rs] = m2;
      str[rs] = rsqrtf(vv + 1e-5f);
    }
    __syncthreads();

    #pragma unroll
    for (int ci = 0; ci < 2; ++ci)
      #pragma unroll
      for (int j = 0; j < 4; ++j) {
        int lrow = wr * 16 + lj * 4 + j;
        int row = row0 + lrow;
        int col = col0 + wc * 32 + ci * 16 + lc2;
        float m2 = stm[lrow], rs2 = str[lrow];
        float pre = rs2 * (p.Psem[(size_t)row * D + col] + acc2[ci][j])
                    - m2 * rs2 * p.c1[col] + p.c2p[col];
        float gl = 0.5f * pre * (1.f + erff(pre * 0.70710678118654752f));
        hidW[(size_t)row * D + col] = f2bf(gl);
      }
  }
  __syncthreads();

  // ---------------- phase 3: sem(t-2) ----------------
  if (t >= 2) {
    const int ts = t - 2;
    const u16* hidR = (ts & 1) ? p.hid1 : p.hid0;
    constexpr int BUFB = 12288;
    const int row0 = blockIdx.x * 32, col0 = blockIdx.y * 64;

    auto stg = [&](int b, int kt){
      char* As = smem + b * BUFB;
      char* Bs = As + 4096;
      { int pr = tid >> 3, pcc = tid & 7, lch = pcc ^ (pr & 7);
        gload_lds16(hidR + (size_t)(row0 + pr) * D + kt * 64 + lch * 8,
                    As + wid * 1024); }
      #pragma unroll
      for (int it = 0; it < 2; ++it) {
        int s = it * 256 + tid, pr = s >> 3, pcc = s & 7;
        int lch = pcc ^ (pr & 7);
        gload_lds16(p.w2 + (size_t)(col0 + pr) * D + kt * 64 + lch * 8,
                    Bs + it * 4096 + wid * 1024);
      }
    };

    stg(0, 0);
    __syncthreads();
    int buf = 0;
    f32x4 acc3[2] = {};
    for (int kt = 0; kt < 8; ++kt) {
      if (kt < 7) stg(buf ^ 1, kt + 1);
      const char* As = smem + buf * BUFB;
      const char* Bs = As + 4096;
      #pragma unroll
      for (int kk = 0; kk < 2; ++kk) {
        int ch = kk * 4 + hi2;
        int ra = wr * 16 + lc;
        bf16x8 af = *(const bf16x8*)(As + ra * 128 + ((ch ^ (ra & 7)) << 4));
        #pragma unroll
        for (int ci = 0; ci < 2; ++ci) {
          int rb = wc * 32 + ci * 16 + lc;
          bf16x8 bb = *(const bf16x8*)(Bs + rb * 128 + ((ch ^ (rb & 7)) << 4));
          acc3[ci] = mfma16(af, bb, acc3[ci]);
        }
      }
      __syncthreads();
      buf ^= 1;
    }

    #pragma unroll
    for (int ci = 0; ci < 2; ++ci)
      #pragma unroll
      for (int j = 0; j < 4; ++j) {
        int row = row0 + wr * 16 + lj * 4 + j;
        int col = col0 + wc * 32 + ci * 16 + lc2;
        float v = p.zsem[(size_t)row * D + col] + acc3[ci][j] + p.b2[col];
        __builtin_nontemporal_store(v, &p.sems[((size_t)row * H + ts) * D + col]);
      }
  }
}

// ---------------------------------------------------------------------------
extern "C" void kernel_launch(void* const* d_in, const int* in_sizes, int n_in,
                              void* d_out, int out_size, void* d_ws, size_t ws_size,
                              hipStream_t stream)
{
  (void)in_sizes; (void)n_in; (void)out_size; (void)ws_size;
  const float* z_dyn = (const float*)d_in[0];
  const float* z_sem = (const float*)d_in[1];
  const float* te_w  = (const float*)d_in[2];
  const float* w_ih  = (const float*)d_in[3];
  const float* w_hh  = (const float*)d_in[4];
  const float* b_ih  = (const float*)d_in[5];
  const float* b_hh  = (const float*)d_in[6];
  const float* ln_g  = (const float*)d_in[7];
  const float* ln_b  = (const float*)d_in[8];
  const float* ln2_g = (const float*)d_in[9];
  const float* ln2_b = (const float*)d_in[10];
  const float* w1    = (const float*)d_in[11];
  const float* b1    = (const float*)d_in[12];
  const float* w2    = (const float*)d_in[13];
  const float* b2    = (const float*)d_in[14];

  char* ws = (char*)d_ws;
  const size_t MB = 1ull << 20;
  float* h0     = (float*)(ws + 0);                  // 4 MB
  float* h1     = (float*)(ws + 4 * MB);             // 4 MB
  u16*  hbh0    = (u16*)(ws + 8 * MB);               // 2 MB
  u16*  hbh1    = (u16*)(ws + 10 * MB);              // 2 MB
  u16*  hbl0    = (u16*)(ws + 12 * MB);              // 2 MB
  u16*  hbl1    = (u16*)(ws + 14 * MB);              // 2 MB
  float* G0     = (float*)(ws + 16 * MB);            // 12 MB
  float* Psem   = (float*)(ws + 28 * MB);            // 4 MB
  u16*  sem_hi  = (u16*)(ws + 32 * MB);              // 2 MB
  u16*  sem_lo  = (u16*)(ws + 34 * MB);              // 2 MB
  u16*  hid0    = (u16*)(ws + 36 * MB);              // 2 MB
  u16*  hid1    = (u16*)(ws + 38 * MB);              // 2 MB
  u16*  wih_hi  = (u16*)(ws + 40 * MB);              // 1.5 MB
  u16*  wih_lo  = (u16*)(ws + 40 * MB + 1572864);    // 1.5 MB
  u16*  whh_hi  = (u16*)(ws + 43 * MB);              // 1.5 MB
  u16*  whh_lo  = (u16*)(ws + 43 * MB + 1572864);    // 1.5 MB
  u16*  W1s     = (u16*)(ws + 46 * MB);              // 512 KB
  u16*  W1h     = (u16*)(ws + 46 * MB + 524288);     // 512 KB
  u16*  w2bf    = (u16*)(ws + 47 * MB);              // 512 KB
  float* c1     = (float*)(ws + 47 * MB + 524288);
  float* c2p    = (float*)(ws + 47 * MB + 528384);
  float* Ssem   = (float*)(ws + 47 * MB + 540672);
  float* Ssem2  = (float*)(ws + 47 * MB + 557056);
  float* Tg     = (float*)(ws + 48 * MB);            // 192 KB

  float* outp = (float*)d_out;
  float* out_dyn  = outp;
  float* out_sems = outp + OUT_HALF;

  prep_kernel<<<4096, 256, 0, stream>>>(
      z_dyn, z_sem, te_w, w_ih, w_hh, ln2_g, ln2_b, w1, b1, w2,
      h1, hbh1, hbl1, sem_hi, sem_lo, wih_hi, wih_lo, whh_hi, whh_lo,
      W1s, W1h, w2bf, c1, c2p, Tg);
  rowstats_kernel<<<512, 256, 0, stream>>>(z_sem, Ssem, Ssem2);
  setup_kernel<<<dim3(32, 32), 256, 0, stream>>>(
      sem_hi, sem_lo, wih_hi, wih_lo, W1s, G0, Psem, b_ih);

  SP p;
  p.hbh0 = hbh0; p.hbh1 = hbh1; p.hbl0 = hbl0; p.hbl1 = hbl1;
  p.hid0 = hid0; p.hid1 = hid1;
  p.h0 = h0; p.h1 = h1;
  p.dyn = out_dyn; p.sems = out_sems;
  p.whh_hi = whh_hi; p.whh_lo = whh_lo; p.W1h = W1h; p.w2 = w2bf;
  p.G0 = G0; p.Tg = Tg; p.bhh = b_hh;
  p.ln_g = ln_g; p.ln_b = ln_b; p.Ssem = Ssem; p.Ssem2 = Ssem2;
  p.Psem = Psem; p.c1 = c1; p.c2p = c2p; p.zsem = z_sem; p.b2 = b2;

  for (int t = 0; t < H + 2; ++t)
    step_kernel<<<dim3(64, 8), 256, 0, stream>>>(p, t);
}

// Round 10
// 843.589 us; speedup vs baseline: 1.5604x; 1.5604x over previous
//
#include <hip/hip_runtime.h>
#include <math.h>

// ---------------------------------------------------------------------------
// TemporalUnitRolloutV341 — GRU rollout, 32 steps over 2048 rows of D=512.
// R10: R9 architecture (one dispatch/step, 4 CONCURRENT block ranges:
// gates(t) || stats(t-1)+dyn || hidGEMM(t-2) || sem(t-3); LN1 hoisted as
// ln1(h)@W1h = rsd1*(h@W1g) - m1*rsd1*d1 + d2) with two fixes:
//   (1) n-gate: n = tanh(inn + r*(h@Whh_n + b_hh_n))  [R9 mis-folded the
//       matmul term outside the r-multiply]
//   (2) fp32 h ping-pong restored for stats/dyn/hprev (R8-grade numerics
//       on the rsd-amplified LN path); GEMM A-operands stay hi+lo bf16.
// ---------------------------------------------------------------------------

typedef unsigned short u16;
using bf16x8 = __attribute__((ext_vector_type(8))) short;
using f32x4  = __attribute__((ext_vector_type(4))) float;

#define DEV __device__ __forceinline__

constexpr int D   = 512;
constexpr int D3  = 1536;
constexpr int H   = 32;
constexpr int BU  = 2048;
constexpr long long OUT_HALF = (long long)BU * H * D;

DEV u16 f2bf(float x){
  union { float f; unsigned u; } c; c.f = x;
  unsigned u = c.u;
  u += 0x7fffu + ((u >> 16) & 1u);
  return (u16)(u >> 16);
}
DEV float bf2f(u16 b){
  union { unsigned u; float f; } c; c.u = ((unsigned)b) << 16; return c.f;
}

DEV void gload_lds16(const void* g, void* l){
  __builtin_amdgcn_global_load_lds(
      (const __attribute__((address_space(1))) void*)g,
      (__attribute__((address_space(3))) void*)l, 16, 0, 0);
}

DEV f32x4 mfma16(bf16x8 a, bf16x8 b, f32x4 c){
  return __builtin_amdgcn_mfma_f32_16x16x32_bf16(a, b, c, 0, 0, 0);
}

DEV float sigm(float x){ return 1.f / (1.f + expf(-x)); }

// ---------------------------------------------------------------------------
// prep: hi/lo splits, W1s, W1g, c1/c2p/d1/d2, Tg, initial state.
// ---------------------------------------------------------------------------
__global__ __launch_bounds__(256) void prep_kernel(
    const float* __restrict__ z_dyn, const float* __restrict__ z_sem,
    const float* __restrict__ te_w,  const float* __restrict__ w_ih,
    const float* __restrict__ w_hh,  const float* __restrict__ ln_g,
    const float* __restrict__ ln_b,  const float* __restrict__ ln2_g,
    const float* __restrict__ ln2_b, const float* __restrict__ w1,
    const float* __restrict__ b1,    const float* __restrict__ w2,
    float* __restrict__ h1, u16* __restrict__ hbh2, u16* __restrict__ hbl2,
    u16* __restrict__ sem_hi, u16* __restrict__ sem_lo,
    u16* __restrict__ wih_hi, u16* __restrict__ wih_lo,
    u16* __restrict__ whh_hi, u16* __restrict__ whh_lo,
    u16* __restrict__ W1s, u16* __restrict__ W1g, u16* __restrict__ w2bf,
    float* __restrict__ c1, float* __restrict__ c2p,
    float* __restrict__ d1, float* __restrict__ d2, float* __restrict__ Tg)
{
  int i = blockIdx.x * 256 + threadIdx.x;
  if (i < BU * D) {
    float hv = z_dyn[i];
    h1[i] = hv;
    u16 hh = f2bf(hv);
    hbh2[i] = hh;
    hbl2[i] = f2bf(hv - bf2f(hh));
    float sv = z_sem[i];
    u16 sh_ = f2bf(sv);
    sem_hi[i] = sh_;
    sem_lo[i] = f2bf(sv - bf2f(sh_));
  }
  if (i < D3 * D) {
    float wv = w_ih[i];
    u16 wh = f2bf(wv);
    wih_hi[i] = wh;
    wih_lo[i] = f2bf(wv - bf2f(wh));
    float uv = w_hh[i];
    u16 uh = f2bf(uv);
    whh_hi[i] = uh;
    whh_lo[i] = f2bf(uv - bf2f(uh));
  }
  if (i < D * D) {
    int k = i >> 9, j = i & 511;
    W1s[i]  = f2bf(w1[k * 1024 + j] * ln2_g[j]);
    w2bf[i] = f2bf(w2[i]);
  }
  if (i < D) {
    float sc1 = 0.f, sc2 = 0.f, sd1 = 0.f, sd2 = 0.f;
    for (int j = 0; j < 512; ++j) {
      float wA = w1[i * 1024 + j];
      float wB = w1[i * 1024 + 512 + j];
      sc1 += wA * ln2_g[j] + wB * ln2_g[512 + j];
      sc2 += wA * ln2_b[j] + wB * ln2_b[512 + j];
      float wBg = wB * ln2_g[512 + j];          // = W1h[i][j]
      float wg = wBg * ln_g[j];                 // = W1g[i][j]
      sd1 += wg;
      sd2 += wBg * ln_b[j];
      W1g[i * 512 + j] = f2bf(wg);
    }
    c1[i] = sc1;
    c2p[i] = sc2 + b1[i];
    d1[i] = sd1;
    d2[i] = sd2;
  }
  if (i < H * D3) {
    int t = i / D3, c = i % D3;
    float s = 0.f;
    for (int d0 = 0; d0 < D; ++d0) s += te_w[t * D + d0] * w_ih[c * D + d0];
    Tg[i] = s;
  }
}

// Per-row sums of sem and sem^2 (ln2 stats split). One wave per row.
__global__ __launch_bounds__(256) void rowstats_kernel(
    const float* __restrict__ sem, float* __restrict__ Ssem,
    float* __restrict__ Ssem2)
{
  const int wid = threadIdx.x >> 6, lane = threadIdx.x & 63;
  const int row = blockIdx.x * 4 + wid;
  const float* p = sem + (size_t)row * D + lane * 8;
  float4 a0 = *(const float4*)p;
  float4 a1 = *(const float4*)(p + 4);
  float s  = a0.x + a0.y + a0.z + a0.w + a1.x + a1.y + a1.z + a1.w;
  float s2 = a0.x*a0.x + a0.y*a0.y + a0.z*a0.z + a0.w*a0.w
           + a1.x*a1.x + a1.y*a1.y + a1.z*a1.z + a1.w*a1.w;
  #pragma unroll
  for (int o = 1; o < 64; o <<= 1) { s += __shfl_xor(s, o); s2 += __shfl_xor(s2, o); }
  if (lane == 0) { Ssem[row] = s; Ssem2[row] = s2; }
}

// ---------------------------------------------------------------------------
// Setup GEMMs: grid (32, 32). by<24 -> G0 tile (bf16x3, +b_ih);
// by>=24 -> Psem tile (plain bf16). 64x64 NT, single-buffered 32KB LDS.
// ---------------------------------------------------------------------------
__global__ __launch_bounds__(256) void setup_kernel(
    const u16* __restrict__ sem_hi, const u16* __restrict__ sem_lo,
    const u16* __restrict__ wih_hi, const u16* __restrict__ wih_lo,
    const u16* __restrict__ W1s, float* __restrict__ G0,
    float* __restrict__ Psem, const float* __restrict__ b_ih)
{
  __shared__ __align__(16) char smem[32768];
  char* Ah = smem;
  char* Al = smem + 8192;
  char* Bh = smem + 16384;
  char* Bl = smem + 24576;
  const int tid = threadIdx.x, wid = tid >> 6, lane = tid & 63;
  const int wr = wid >> 1, wc = wid & 1;
  const bool isG0 = blockIdx.y < 24;
  const u16* Bsrc = isG0 ? wih_hi : W1s;
  const int row0 = blockIdx.x * 64;
  const int col0 = (isG0 ? blockIdx.y : blockIdx.y - 24) * 64;

  f32x4 acc[2][2] = {};
  for (int kt = 0; kt < 8; ++kt) {
    #pragma unroll
    for (int it = 0; it < 2; ++it) {
      int s = it * 256 + tid, pr = s >> 3, pc = s & 7;
      int lch = pc ^ (pr & 7);
      size_t aoff = (size_t)(row0 + pr) * D + kt * 64 + lch * 8;
      size_t boff = (size_t)(col0 + pr) * D + kt * 64 + lch * 8;
      gload_lds16(sem_hi + aoff, Ah + it * 4096 + wid * 1024);
      gload_lds16(Bsrc + boff,   Bh + it * 4096 + wid * 1024);
      if (isG0) {
        gload_lds16(sem_lo + aoff, Al + it * 4096 + wid * 1024);
        gload_lds16(wih_lo + boff, Bl + it * 4096 + wid * 1024);
      }
    }
    asm volatile("s_waitcnt vmcnt(0)" ::: "memory");
    __syncthreads();

    const int lc = lane & 15, hi2 = lane >> 4;
    #pragma unroll
    for (int kk = 0; kk < 2; ++kk) {
      int ch = kk * 4 + hi2;
      bf16x8 afh[2], afl[2], bfh[2], bfl[2];
      #pragma unroll
      for (int mi = 0; mi < 2; ++mi) {
        int r = wr * 32 + mi * 16 + lc;
        int o = r * 128 + ((ch ^ (r & 7)) << 4);
        afh[mi] = *(const bf16x8*)(Ah + o);
        if (isG0) afl[mi] = *(const bf16x8*)(Al + o);
      }
      #pragma unroll
      for (int ci = 0; ci < 2; ++ci) {
        int r = wc * 32 + ci * 16 + lc;
        int o = r * 128 + ((ch ^ (r & 7)) << 4);
        bfh[ci] = *(const bf16x8*)(Bh + o);
        if (isG0) bfl[ci] = *(const bf16x8*)(Bl + o);
      }
      #pragma unroll
      for (int mi = 0; mi < 2; ++mi)
        #pragma unroll
        for (int ci = 0; ci < 2; ++ci) {
          f32x4 a = acc[mi][ci];
          a = mfma16(afh[mi], bfh[ci], a);
          if (isG0) {
            a = mfma16(afl[mi], bfh[ci], a);
            a = mfma16(afh[mi], bfl[ci], a);
          }
          acc[mi][ci] = a;
        }
    }
    __syncthreads();
  }
  const int lj = lane >> 4, lc2 = lane & 15;
  #pragma unroll
  for (int mi = 0; mi < 2; ++mi)
    #pragma unroll
    for (int ci = 0; ci < 2; ++ci)
      #pragma unroll
      for (int j = 0; j < 4; ++j) {
        int row = row0 + wr * 32 + mi * 16 + lj * 4 + j;
        int col = col0 + wc * 32 + ci * 16 + lc2;
        float v = acc[mi][ci][j];
        if (isG0) G0[(size_t)row * D3 + col] = v + b_ih[col];
        else      Psem[(size_t)row * D + col] = v;
      }
}

// ---------------------------------------------------------------------------
// Fused step dispatch: 1152 blocks, 4 concurrent ranges.
//   [0,512):    gates(t)      (t<32)     64 rows x 32 cols x 3 gates, bf16x3
//   [512,768):  hidGEMM(t-2)  (2<=t<=33) 64x64, A=hb hi+lo, B=W1g
//   [768,1024): sem(t-3)      (t>=3)     64x64 plain
//   [1024,1152):stats(t-1)+dyn(1<=t<=32) 16 rows/block, fp32 h, two-pass
// ---------------------------------------------------------------------------
__global__ __launch_bounds__(256, 4) void fused_kernel(
    int t,
    // gates
    const u16* __restrict__ hbh_in, const u16* __restrict__ hbl_in,
    u16* __restrict__ hbh_out, u16* __restrict__ hbl_out,
    const float* __restrict__ hf_in, float* __restrict__ hf_out,
    const u16* __restrict__ whh_hi, const u16* __restrict__ whh_lo,
    const float* __restrict__ G0, const float* __restrict__ Tg,
    const float* __restrict__ bhh,
    // stats(t-1): reads hf_in (slot t-1)
    float4* __restrict__ stats_w, float* __restrict__ dyn,
    const float* __restrict__ ln_g, const float* __restrict__ ln_b,
    const float* __restrict__ Ssem, const float* __restrict__ Ssem2,
    // hidGEMM(t-2)
    const u16* __restrict__ lbh, const u16* __restrict__ lbl,
    const float4* __restrict__ stats_r, const u16* __restrict__ W1g,
    const float* __restrict__ Psem, const float* __restrict__ d1,
    const float* __restrict__ d2, const float* __restrict__ c1,
    const float* __restrict__ c2p, u16* __restrict__ hid_w,
    // sem(t-3)
    const u16* __restrict__ hid_r, const u16* __restrict__ w2bf,
    const float* __restrict__ zsem, const float* __restrict__ b2,
    float* __restrict__ sems)
{
  __shared__ __align__(16) char smem[40960];
  const int bid = blockIdx.x;
  const int tid = threadIdx.x, wid = tid >> 6, lane = tid & 63;
  const int wr = wid >> 1, wc = wid & 1;
  const int lc = lane & 15, hi2 = lane >> 4;
  const int lj = lane >> 4, lc2 = lane & 15;

  if (bid < 512) {
    // ----------------- gates(t): 64 rows x (32 cols x 3 gates) -------------
    if (t >= H) return;
    const int row0 = (bid & 31) * 64;
    const int gc   = (bid >> 5) * 32;
    char* Ah = smem;             // 8 KB
    char* Al = smem + 8192;      // 8 KB
    char* Bh = smem + 16384;     // 12 KB (96 rows)
    char* Bl = smem + 28672;     // 12 KB
    f32x4 acc[3][2] = {};

    for (int kt = 0; kt < 8; ++kt) {
      #pragma unroll
      for (int it = 0; it < 2; ++it) {
        int s = it * 256 + tid, pr = s >> 3, pc = s & 7;
        int lch = pc ^ (pr & 7);
        size_t off = (size_t)(row0 + pr) * D + kt * 64 + lch * 8;
        gload_lds16(hbh_in + off, Ah + it * 4096 + wid * 1024);
        gload_lds16(hbl_in + off, Al + it * 4096 + wid * 1024);
      }
      #pragma unroll
      for (int it = 0; it < 3; ++it) {
        int s = it * 256 + tid, pr = s >> 3, pc = s & 7;
        int lch = pc ^ (pr & 7);
        int g = pr >> 5, lr = pr & 31;
        size_t off = (size_t)(g * D + gc + lr) * D + kt * 64 + lch * 8;
        gload_lds16(whh_hi + off, Bh + it * 4096 + wid * 1024);
        gload_lds16(whh_lo + off, Bl + it * 4096 + wid * 1024);
      }
      asm volatile("s_waitcnt vmcnt(0)" ::: "memory");
      __syncthreads();

      #pragma unroll
      for (int kk = 0; kk < 2; ++kk) {
        int ch = kk * 4 + hi2;
        bf16x8 afh[2], afl[2];
        #pragma unroll
        for (int mi = 0; mi < 2; ++mi) {
          int r = wr * 32 + mi * 16 + lc;
          int o = r * 128 + ((ch ^ (r & 7)) << 4);
          afh[mi] = *(const bf16x8*)(Ah + o);
          afl[mi] = *(const bf16x8*)(Al + o);
        }
        #pragma unroll
        for (int g = 0; g < 3; ++g) {
          int rb = g * 32 + wc * 16 + lc;
          int bo = rb * 128 + ((ch ^ (rb & 7)) << 4);
          bf16x8 bh = *(const bf16x8*)(Bh + bo);
          bf16x8 bl = *(const bf16x8*)(Bl + bo);
          #pragma unroll
          for (int mi = 0; mi < 2; ++mi) {
            f32x4 a = acc[g][mi];
            a = mfma16(afh[mi], bh, a);
            a = mfma16(afl[mi], bh, a);
            a = mfma16(afh[mi], bl, a);
            acc[g][mi] = a;
          }
        }
      }
      __syncthreads();
    }

    const int gcol = gc + wc * 16 + lc2;
    const float br = bhh[gcol];
    const float bz = bhh[512 + gcol];
    const float bn = bhh[1024 + gcol];
    #pragma unroll
    for (int mi = 0; mi < 2; ++mi)
      #pragma unroll
      for (int j = 0; j < 4; ++j) {
        int row = row0 + wr * 32 + mi * 16 + lj * 4 + j;
        size_t g0i = (size_t)row * D3 + gcol;
        float gr = G0[g0i]        + Tg[t * D3 + gcol]        + acc[0][mi][j];
        float gz = G0[g0i + 512]  + Tg[t * D3 + 512 + gcol]  + acc[1][mi][j];
        float gn = G0[g0i + 1024] + Tg[t * D3 + 1024 + gcol];   // inn only
        float r = sigm(gr + br);
        float z = sigm(gz + bz);
        float n = tanhf(gn + r * (acc[2][mi][j] + bn));          // FIXED
        size_t hi_ = (size_t)row * D + gcol;
        float hnew = (1.f - z) * n + z * hf_in[hi_];
        hf_out[hi_] = hnew;
        u16 hh = f2bf(hnew);
        hbh_out[hi_] = hh;
        hbl_out[hi_] = f2bf(hnew - bf2f(hh));
      }
  } else if (bid < 768) {
    // ----------------- hidGEMM(t-2): 64 x 64, A = hb hi+lo, B = W1g --------
    if (t < 2 || t > H + 1) return;
    const int i = bid - 512;
    const int row0 = (i & 31) * 64, col0 = (i >> 5) * 64;
    char* Ah = smem;             // 8 KB
    char* Al = smem + 8192;      // 8 KB
    char* Bs = smem + 16384;     // 8 KB
    f32x4 acc[2][2] = {};

    for (int kt = 0; kt < 8; ++kt) {
      #pragma unroll
      for (int it = 0; it < 2; ++it) {
        int s = it * 256 + tid, pr = s >> 3, pc = s & 7;
        int lch = pc ^ (pr & 7);
        size_t aoff = (size_t)(row0 + pr) * D + kt * 64 + lch * 8;
        size_t boff = (size_t)(col0 + pr) * D + kt * 64 + lch * 8;
        gload_lds16(lbh + aoff, Ah + it * 4096 + wid * 1024);
        gload_lds16(lbl + aoff, Al + it * 4096 + wid * 1024);
        gload_lds16(W1g + boff, Bs + it * 4096 + wid * 1024);
      }
      asm volatile("s_waitcnt vmcnt(0)" ::: "memory");
      __syncthreads();

      #pragma unroll
      for (int kk = 0; kk < 2; ++kk) {
        int ch = kk * 4 + hi2;
        bf16x8 afh[2], afl[2], bf[2];
        #pragma unroll
        for (int mi = 0; mi < 2; ++mi) {
          int r = wr * 32 + mi * 16 + lc;
          int o = r * 128 + ((ch ^ (r & 7)) << 4);
          afh[mi] = *(const bf16x8*)(Ah + o);
          afl[mi] = *(const bf16x8*)(Al + o);
        }
        #pragma unroll
        for (int ci = 0; ci < 2; ++ci) {
          int r = wc * 32 + ci * 16 + lc;
          bf[ci] = *(const bf16x8*)(Bs + r * 128 + ((ch ^ (r & 7)) << 4));
        }
        #pragma unroll
        for (int mi = 0; mi < 2; ++mi)
          #pragma unroll
          for (int ci = 0; ci < 2; ++ci) {
            f32x4 a = acc[mi][ci];
            a = mfma16(afh[mi], bf[ci], a);
            a = mfma16(afl[mi], bf[ci], a);
            acc[mi][ci] = a;
          }
      }
      __syncthreads();
    }

    #pragma unroll
    for (int mi = 0; mi < 2; ++mi)
      #pragma unroll
      for (int ci = 0; ci < 2; ++ci)
        #pragma unroll
        for (int j = 0; j < 4; ++j) {
          int row = row0 + wr * 32 + mi * 16 + lj * 4 + j;
          int col = col0 + wc * 32 + ci * 16 + lc2;
          float4 st = stats_r[row];   // {rsd1, m1*rsd1, rs2, m2*rs2}
          float hn_w1 = st.x * acc[mi][ci][j] - st.y * d1[col] + d2[col];
          float pre = st.z * (Psem[(size_t)row * D + col] + hn_w1)
                      - st.w * c1[col] + c2p[col];
          float gl = 0.5f * pre * (1.f + erff(pre * 0.70710678118654752f));
          hid_w[(size_t)row * D + col] = f2bf(gl);
        }
  } else if (bid < 1024) {
    // ----------------- sem(t-3): 64 x 64 plain ------------------------------
    if (t < 3) return;
    const int ts = t - 3;
    const int i = bid - 768;
    const int row0 = (i & 31) * 64, col0 = (i >> 5) * 64;
    char* As = smem;             // 8 KB
    char* Bs = smem + 8192;      // 8 KB
    f32x4 acc[2][2] = {};

    for (int kt = 0; kt < 8; ++kt) {
      #pragma unroll
      for (int it = 0; it < 2; ++it) {
        int s = it * 256 + tid, pr = s >> 3, pc = s & 7;
        int lch = pc ^ (pr & 7);
        gload_lds16(hid_r + (size_t)(row0 + pr) * D + kt * 64 + lch * 8,
                    As + it * 4096 + wid * 1024);
        gload_lds16(w2bf + (size_t)(col0 + pr) * D + kt * 64 + lch * 8,
                    Bs + it * 4096 + wid * 1024);
      }
      asm volatile("s_waitcnt vmcnt(0)" ::: "memory");
      __syncthreads();

      #pragma unroll
      for (int kk = 0; kk < 2; ++kk) {
        int ch = kk * 4 + hi2;
        bf16x8 af[2], bf[2];
        #pragma unroll
        for (int mi = 0; mi < 2; ++mi) {
          int r = wr * 32 + mi * 16 + lc;
          af[mi] = *(const bf16x8*)(As + r * 128 + ((ch ^ (r & 7)) << 4));
        }
        #pragma unroll
        for (int ci = 0; ci < 2; ++ci) {
          int r = wc * 32 + ci * 16 + lc;
          bf[ci] = *(const bf16x8*)(Bs + r * 128 + ((ch ^ (r & 7)) << 4));
        }
        #pragma unroll
        for (int mi = 0; mi < 2; ++mi)
          #pragma unroll
          for (int ci = 0; ci < 2; ++ci)
            acc[mi][ci] = mfma16(af[mi], bf[ci], acc[mi][ci]);
      }
      __syncthreads();
    }

    #pragma unroll
    for (int mi = 0; mi < 2; ++mi)
      #pragma unroll
      for (int ci = 0; ci < 2; ++ci)
        #pragma unroll
        for (int j = 0; j < 4; ++j) {
          int row = row0 + wr * 32 + mi * 16 + lj * 4 + j;
          int col = col0 + wc * 32 + ci * 16 + lc2;
          float v = zsem[(size_t)row * D + col] + acc[mi][ci][j] + b2[col];
          __builtin_nontemporal_store(
              v, &sems[((size_t)row * H + ts) * D + col]);
        }
  } else {
    // ----------------- stats(t-1) + dyn(t-1): 16 rows/block, fp32 h --------
    if (t < 1 || t > H) return;
    const int tt = t - 1;
    const int base = (bid - 1024) * 16 + wid * 4;
    const float4 g0 = *(const float4*)(ln_g + lane * 8);
    const float4 g1 = *(const float4*)(ln_g + lane * 8 + 4);
    const float4 b0 = *(const float4*)(ln_b + lane * 8);
    const float4 b1v = *(const float4*)(ln_b + lane * 8 + 4);
    const float gg[8] = {g0.x,g0.y,g0.z,g0.w,g1.x,g1.y,g1.z,g1.w};
    const float bb[8] = {b0.x,b0.y,b0.z,b0.w,b1v.x,b1v.y,b1v.z,b1v.w};

    for (int rr = 0; rr < 4; ++rr) {
      const int row = base + rr;
      const float* hp = hf_in + (size_t)row * D + lane * 8;
      float4 a0 = *(const float4*)hp, a1 = *(const float4*)(hp + 4);
      float h[8] = {a0.x, a0.y, a0.z, a0.w, a1.x, a1.y, a1.z, a1.w};
      float s1 = 0.f;
      #pragma unroll
      for (int k = 0; k < 8; ++k) s1 += h[k];
      #pragma unroll
      for (int o = 1; o < 64; o <<= 1) s1 += __shfl_xor(s1, o);
      float m1 = s1 * (1.f / 512.f);
      float s2 = 0.f;
      #pragma unroll
      for (int k = 0; k < 8; ++k) {
        float dv = h[k] - m1;
        s2 += dv * dv;
      }
      #pragma unroll
      for (int o = 1; o < 64; o <<= 1) s2 += __shfl_xor(s2, o);
      float rsd1 = rsqrtf(s2 * (1.f / 512.f) + 1e-5f);

      float hn[8];
      float sh = 0.f, sh2 = 0.f;
      #pragma unroll
      for (int k = 0; k < 8; ++k) {
        float x = (h[k] - m1) * rsd1 * gg[k] + bb[k];
        hn[k] = x; sh += x; sh2 += x * x;
      }
      float* dp = dyn + ((size_t)row * H + tt) * D + lane * 8;
      f32x4 v0 = {hn[0], hn[1], hn[2], hn[3]};
      f32x4 v1 = {hn[4], hn[5], hn[6], hn[7]};
      __builtin_nontemporal_store(v0, (f32x4*)dp);
      __builtin_nontemporal_store(v1, (f32x4*)(dp + 4));

      #pragma unroll
      for (int o = 1; o < 64; o <<= 1) {
        sh += __shfl_xor(sh, o); sh2 += __shfl_xor(sh2, o);
      }
      if (lane == 0) {
        float m2 = (Ssem[row] + sh) * (1.f / 1024.f);
        float vv = (Ssem2[row] + sh2) * (1.f / 1024.f) - m2 * m2;
        float rs2 = rsqrtf(vv + 1e-5f);
        stats_w[row] = make_float4(rsd1, m1 * rsd1, rs2, m2 * rs2);
      }
    }
  }
}

// ---------------------------------------------------------------------------
extern "C" void kernel_launch(void* const* d_in, const int* in_sizes, int n_in,
                              void* d_out, int out_size, void* d_ws, size_t ws_size,
                              hipStream_t stream)
{
  (void)in_sizes; (void)n_in; (void)out_size; (void)ws_size;
  const float* z_dyn = (const float*)d_in[0];
  const float* z_sem = (const float*)d_in[1];
  const float* te_w  = (const float*)d_in[2];
  const float* w_ih  = (const float*)d_in[3];
  const float* w_hh  = (const float*)d_in[4];
  const float* b_ih  = (const float*)d_in[5];
  const float* b_hh  = (const float*)d_in[6];
  const float* ln_g  = (const float*)d_in[7];
  const float* ln_b  = (const float*)d_in[8];
  const float* ln2_g = (const float*)d_in[9];
  const float* ln2_b = (const float*)d_in[10];
  const float* w1    = (const float*)d_in[11];
  const float* b1    = (const float*)d_in[12];
  const float* w2    = (const float*)d_in[13];
  const float* b2    = (const float*)d_in[14];

  char* ws = (char*)d_ws;
  const size_t MB = 1ull << 20;
  u16* hbh[3] = { (u16*)(ws + 0),      (u16*)(ws + 2 * MB),  (u16*)(ws + 4 * MB) };
  u16* hbl[3] = { (u16*)(ws + 6 * MB), (u16*)(ws + 8 * MB),  (u16*)(ws + 10 * MB) };
  float* G0     = (float*)(ws + 12 * MB);            // 12 MB
  float* Psem   = (float*)(ws + 25 * MB);            // 4 MB
  u16*  sem_hi  = (u16*)(ws + 29 * MB);              // 2 MB
  u16*  sem_lo  = (u16*)(ws + 31 * MB);              // 2 MB
  u16*  hid0    = (u16*)(ws + 33 * MB);              // 2 MB
  u16*  hid1    = (u16*)(ws + 35 * MB);              // 2 MB
  u16*  wih_hi  = (u16*)(ws + 37 * MB);              // 1.5 MB
  u16*  wih_lo  = (u16*)(ws + 37 * MB + 1572864);    // 1.5 MB
  u16*  whh_hi  = (u16*)(ws + 40 * MB);              // 1.5 MB
  u16*  whh_lo  = (u16*)(ws + 40 * MB + 1572864);    // 1.5 MB
  u16*  W1s     = (u16*)(ws + 43 * MB);              // 512 KB
  u16*  W1g     = (u16*)(ws + 43 * MB + 524288);     // 512 KB
  u16*  w2bf    = (u16*)(ws + 44 * MB);              // 512 KB
  float* c1     = (float*)(ws + 45 * MB);
  float* c2p    = (float*)(ws + 45 * MB + 16384);
  float* d1     = (float*)(ws + 45 * MB + 32768);
  float* d2     = (float*)(ws + 45 * MB + 49152);
  float* Ssem   = (float*)(ws + 45 * MB + 65536);
  float* Ssem2  = (float*)(ws + 45 * MB + 81920);
  float4* stats0 = (float4*)(ws + 46 * MB);          // 32 KB
  float4* stats1 = (float4*)(ws + 46 * MB + 32768);  // 32 KB
  float* Tg     = (float*)(ws + 47 * MB);            // 192 KB
  float* hf0    = (float*)(ws + 48 * MB);            // 4 MB
  float* hf1    = (float*)(ws + 52 * MB);            // 4 MB

  float* outp = (float*)d_out;
  float* out_dyn  = outp;
  float* out_sems = outp + OUT_HALF;

  // initial state h(-1): hb slot 2 (== (-1) mod 3), hf slot 1 (== (-1) & 1)
  prep_kernel<<<4096, 256, 0, stream>>>(
      z_dyn, z_sem, te_w, w_ih, w_hh, ln_g, ln_b, ln2_g, ln2_b, w1, b1, w2,
      hf1, hbh[2], hbl[2], sem_hi, sem_lo, wih_hi, wih_lo, whh_hi, whh_lo,
      W1s, W1g, w2bf, c1, c2p, d1, d2, Tg);
  rowstats_kernel<<<512, 256, 0, stream>>>(z_sem, Ssem, Ssem2);
  setup_kernel<<<dim3(32, 32), 256, 0, stream>>>(
      sem_hi, sem_lo, wih_hi, wih_lo, W1s, G0, Psem, b_ih);

  for (int t = 0; t <= H + 2; ++t) {
    int s_out  = ((t % 3) + 3) % 3;          // gates write hb slot(t)
    int s_in   = (((t - 1) % 3) + 3) % 3;    // gates read hb slot(t-1)
    int s_ln   = (((t - 2) % 3) + 3) % 3;    // hidGEMM reads hb slot(t-2)
    float* hf_out      = (t & 1) ? hf1 : hf0;
    const float* hf_in = (t & 1) ? hf0 : hf1;   // slot (t-1)&1
    float4* st_w = ((t - 1) & 1) ? stats1 : stats0;
    const float4* st_r = ((t - 2) & 1) ? stats1 : stats0;
    u16* hidw = ((t - 2) & 1) ? hid1 : hid0;
    const u16* hidr = ((t - 3) & 1) ? hid1 : hid0;

    fused_kernel<<<dim3(1152), dim3(256), 0, stream>>>(
        t,
        hbh[s_in], hbl[s_in], hbh[s_out], hbl[s_out],
        hf_in, hf_out,
        whh_hi, whh_lo, G0, Tg, b_hh,
        st_w, out_dyn, ln_g, ln_b, Ssem, Ssem2,
        hbh[s_ln], hbl[s_ln], st_r, W1g, Psem, d1, d2, c1, c2p, hidw,
        hidr, w2bf, z_sem, b2, out_sems);
  }
}

// Round 11
// 739.510 us; speedup vs baseline: 1.7800x; 1.1407x over previous
//
#include <hip/hip_runtime.h>
#include <math.h>

// ---------------------------------------------------------------------------
// TemporalUnitRolloutV341 — GRU rollout, 32 steps over 2048 rows of D=512.
// R11 = R10 (one dispatch/step, 4 concurrent block ranges, LN1 hoisted) +
//   (1) broadcast-friendly Tg precompute (R10's was stride-2KB uncoalesced)
//   (2) MFMA cuts justified by error analysis: r/z gates drop the weight-lo
//       term (sigmoid-damped, ~6e-4 steady-state h drift); hidGEMM drops
//       A-lo (non-compounding, ~1e-3 into sems). n-gate keeps full bf16x3.
//       12.9 -> 9.6 GFLOP/step.
//   (3) hid+sem phases double-buffered (T3-minimum: stage kt+1 before
//       compute kt, single barrier per kt — R2's proven pattern).
// ---------------------------------------------------------------------------

typedef unsigned short u16;
using bf16x8 = __attribute__((ext_vector_type(8))) short;
using f32x4  = __attribute__((ext_vector_type(4))) float;

#define DEV __device__ __forceinline__

constexpr int D   = 512;
constexpr int D3  = 1536;
constexpr int H   = 32;
constexpr int BU  = 2048;
constexpr long long OUT_HALF = (long long)BU * H * D;

DEV u16 f2bf(float x){
  union { float f; unsigned u; } c; c.f = x;
  unsigned u = c.u;
  u += 0x7fffu + ((u >> 16) & 1u);
  return (u16)(u >> 16);
}
DEV float bf2f(u16 b){
  union { unsigned u; float f; } c; c.u = ((unsigned)b) << 16; return c.f;
}

DEV void gload_lds16(const void* g, void* l){
  __builtin_amdgcn_global_load_lds(
      (const __attribute__((address_space(1))) void*)g,
      (__attribute__((address_space(3))) void*)l, 16, 0, 0);
}

DEV f32x4 mfma16(bf16x8 a, bf16x8 b, f32x4 c){
  return __builtin_amdgcn_mfma_f32_16x16x32_bf16(a, b, c, 0, 0, 0);
}

DEV float sigm(float x){ return 1.f / (1.f + expf(-x)); }

// ---------------------------------------------------------------------------
// prep: hi/lo splits, W1s, W1g, c1/c2p/d1/d2, Tg, initial state.
// ---------------------------------------------------------------------------
__global__ __launch_bounds__(256) void prep_kernel(
    const float* __restrict__ z_dyn, const float* __restrict__ z_sem,
    const float* __restrict__ te_w,  const float* __restrict__ w_ih,
    const float* __restrict__ w_hh,  const float* __restrict__ ln_g,
    const float* __restrict__ ln_b,  const float* __restrict__ ln2_g,
    const float* __restrict__ ln2_b, const float* __restrict__ w1,
    const float* __restrict__ b1,    const float* __restrict__ w2,
    float* __restrict__ h1, u16* __restrict__ hbh2, u16* __restrict__ hbl2,
    u16* __restrict__ sem_hi, u16* __restrict__ sem_lo,
    u16* __restrict__ wih_hi, u16* __restrict__ wih_lo,
    u16* __restrict__ whh_hi, u16* __restrict__ whh_lo,
    u16* __restrict__ W1s, u16* __restrict__ W1g, u16* __restrict__ w2bf,
    float* __restrict__ c1, float* __restrict__ c2p,
    float* __restrict__ d1, float* __restrict__ d2, float* __restrict__ Tg)
{
  int i = blockIdx.x * 256 + threadIdx.x;
  if (i < BU * D) {
    float hv = z_dyn[i];
    h1[i] = hv;
    u16 hh = f2bf(hv);
    hbh2[i] = hh;
    hbl2[i] = f2bf(hv - bf2f(hh));
    float sv = z_sem[i];
    u16 sh_ = f2bf(sv);
    sem_hi[i] = sh_;
    sem_lo[i] = f2bf(sv - bf2f(sh_));
  }
  if (i < D3 * D) {
    float wv = w_ih[i];
    u16 wh = f2bf(wv);
    wih_hi[i] = wh;
    wih_lo[i] = f2bf(wv - bf2f(wh));
    float uv = w_hh[i];
    u16 uh = f2bf(uv);
    whh_hi[i] = uh;
    whh_lo[i] = f2bf(uv - bf2f(uh));
  }
  if (i < D * D) {
    int k = i >> 9, j = i & 511;
    W1s[i]  = f2bf(w1[k * 1024 + j] * ln2_g[j]);
    w2bf[i] = f2bf(w2[i]);
  }
  if (i < D) {
    float sc1 = 0.f, sc2 = 0.f, sd1 = 0.f, sd2 = 0.f;
    for (int j = 0; j < 512; ++j) {
      float wA = w1[i * 1024 + j];
      float wB = w1[i * 1024 + 512 + j];
      sc1 += wA * ln2_g[j] + wB * ln2_g[512 + j];
      sc2 += wA * ln2_b[j] + wB * ln2_b[512 + j];
      float wBg = wB * ln2_g[512 + j];          // = W1h[i][j]
      float wg = wBg * ln_g[j];                 // = W1g[i][j]
      sd1 += wg;
      sd2 += wBg * ln_b[j];
      W1g[i * 512 + j] = f2bf(wg);
    }
    c1[i] = sc1;
    c2p[i] = sc2 + b1[i];
    d1[i] = sd1;
    d2[i] = sd2;
  }
  if (i < H * D3) {
    // broadcast-friendly: 32 lanes share one w_ih row (uniform load);
    // te_w (64KB) stays L1-resident.
    int c = i >> 5, t = i & 31;
    float s = 0.f;
    for (int d0 = 0; d0 < D; ++d0) s += te_w[t * D + d0] * w_ih[c * D + d0];
    Tg[t * D3 + c] = s;
  }
}

// Per-row sums of sem and sem^2 (ln2 stats split). One wave per row.
__global__ __launch_bounds__(256) void rowstats_kernel(
    const float* __restrict__ sem, float* __restrict__ Ssem,
    float* __restrict__ Ssem2)
{
  const int wid = threadIdx.x >> 6, lane = threadIdx.x & 63;
  const int row = blockIdx.x * 4 + wid;
  const float* p = sem + (size_t)row * D + lane * 8;
  float4 a0 = *(const float4*)p;
  float4 a1 = *(const float4*)(p + 4);
  float s  = a0.x + a0.y + a0.z + a0.w + a1.x + a1.y + a1.z + a1.w;
  float s2 = a0.x*a0.x + a0.y*a0.y + a0.z*a0.z + a0.w*a0.w
           + a1.x*a1.x + a1.y*a1.y + a1.z*a1.z + a1.w*a1.w;
  #pragma unroll
  for (int o = 1; o < 64; o <<= 1) { s += __shfl_xor(s, o); s2 += __shfl_xor(s2, o); }
  if (lane == 0) { Ssem[row] = s; Ssem2[row] = s2; }
}

// ---------------------------------------------------------------------------
// Setup GEMMs: grid (32, 32). by<24 -> G0 tile (bf16x3, +b_ih);
// by>=24 -> Psem tile (plain bf16). 64x64 NT, single-buffered 32KB LDS.
// ---------------------------------------------------------------------------
__global__ __launch_bounds__(256) void setup_kernel(
    const u16* __restrict__ sem_hi, const u16* __restrict__ sem_lo,
    const u16* __restrict__ wih_hi, const u16* __restrict__ wih_lo,
    const u16* __restrict__ W1s, float* __restrict__ G0,
    float* __restrict__ Psem, const float* __restrict__ b_ih)
{
  __shared__ __align__(16) char smem[32768];
  char* Ah = smem;
  char* Al = smem + 8192;
  char* Bh = smem + 16384;
  char* Bl = smem + 24576;
  const int tid = threadIdx.x, wid = tid >> 6, lane = tid & 63;
  const int wr = wid >> 1, wc = wid & 1;
  const bool isG0 = blockIdx.y < 24;
  const u16* Bsrc = isG0 ? wih_hi : W1s;
  const int row0 = blockIdx.x * 64;
  const int col0 = (isG0 ? blockIdx.y : blockIdx.y - 24) * 64;

  f32x4 acc[2][2] = {};
  for (int kt = 0; kt < 8; ++kt) {
    #pragma unroll
    for (int it = 0; it < 2; ++it) {
      int s = it * 256 + tid, pr = s >> 3, pc = s & 7;
      int lch = pc ^ (pr & 7);
      size_t aoff = (size_t)(row0 + pr) * D + kt * 64 + lch * 8;
      size_t boff = (size_t)(col0 + pr) * D + kt * 64 + lch * 8;
      gload_lds16(sem_hi + aoff, Ah + it * 4096 + wid * 1024);
      gload_lds16(Bsrc + boff,   Bh + it * 4096 + wid * 1024);
      if (isG0) {
        gload_lds16(sem_lo + aoff, Al + it * 4096 + wid * 1024);
        gload_lds16(wih_lo + boff, Bl + it * 4096 + wid * 1024);
      }
    }
    asm volatile("s_waitcnt vmcnt(0)" ::: "memory");
    __syncthreads();

    const int lc = lane & 15, hi2 = lane >> 4;
    #pragma unroll
    for (int kk = 0; kk < 2; ++kk) {
      int ch = kk * 4 + hi2;
      bf16x8 afh[2], afl[2], bfh[2], bfl[2];
      #pragma unroll
      for (int mi = 0; mi < 2; ++mi) {
        int r = wr * 32 + mi * 16 + lc;
        int o = r * 128 + ((ch ^ (r & 7)) << 4);
        afh[mi] = *(const bf16x8*)(Ah + o);
        if (isG0) afl[mi] = *(const bf16x8*)(Al + o);
      }
      #pragma unroll
      for (int ci = 0; ci < 2; ++ci) {
        int r = wc * 32 + ci * 16 + lc;
        int o = r * 128 + ((ch ^ (r & 7)) << 4);
        bfh[ci] = *(const bf16x8*)(Bh + o);
        if (isG0) bfl[ci] = *(const bf16x8*)(Bl + o);
      }
      #pragma unroll
      for (int mi = 0; mi < 2; ++mi)
        #pragma unroll
        for (int ci = 0; ci < 2; ++ci) {
          f32x4 a = acc[mi][ci];
          a = mfma16(afh[mi], bfh[ci], a);
          if (isG0) {
            a = mfma16(afl[mi], bfh[ci], a);
            a = mfma16(afh[mi], bfl[ci], a);
          }
          acc[mi][ci] = a;
        }
    }
    __syncthreads();
  }
  const int lj = lane >> 4, lc2 = lane & 15;
  #pragma unroll
  for (int mi = 0; mi < 2; ++mi)
    #pragma unroll
    for (int ci = 0; ci < 2; ++ci)
      #pragma unroll
      for (int j = 0; j < 4; ++j) {
        int row = row0 + wr * 32 + mi * 16 + lj * 4 + j;
        int col = col0 + wc * 32 + ci * 16 + lc2;
        float v = acc[mi][ci][j];
        if (isG0) G0[(size_t)row * D3 + col] = v + b_ih[col];
        else      Psem[(size_t)row * D + col] = v;
      }
}

// ---------------------------------------------------------------------------
// Fused step dispatch: 1152 blocks, 4 concurrent ranges.
//   [0,512):    gates(t)      (t<32)  64r x 32c x 3g; r/z bf16x2, n bf16x3
//   [512,768):  hidGEMM(t-2)           64x64, A=hb hi only, B=W1g, dbuf
//   [768,1024): sem(t-3)               64x64 plain, dbuf
//   [1024,1152):stats(t-1)+dyn         16 rows/block, fp32 h, two-pass
// ---------------------------------------------------------------------------
__global__ __launch_bounds__(256, 4) void fused_kernel(
    int t,
    // gates
    const u16* __restrict__ hbh_in, const u16* __restrict__ hbl_in,
    u16* __restrict__ hbh_out, u16* __restrict__ hbl_out,
    const float* __restrict__ hf_in, float* __restrict__ hf_out,
    const u16* __restrict__ whh_hi, const u16* __restrict__ whh_lo,
    const float* __restrict__ G0, const float* __restrict__ Tg,
    const float* __restrict__ bhh,
    // stats(t-1): reads hf_in (slot t-1)
    float4* __restrict__ stats_w, float* __restrict__ dyn,
    const float* __restrict__ ln_g, const float* __restrict__ ln_b,
    const float* __restrict__ Ssem, const float* __restrict__ Ssem2,
    // hidGEMM(t-2)
    const u16* __restrict__ lbh,
    const float4* __restrict__ stats_r, const u16* __restrict__ W1g,
    const float* __restrict__ Psem, const float* __restrict__ d1,
    const float* __restrict__ d2, const float* __restrict__ c1,
    const float* __restrict__ c2p, u16* __restrict__ hid_w,
    // sem(t-3)
    const u16* __restrict__ hid_r, const u16* __restrict__ w2bf,
    const float* __restrict__ zsem, const float* __restrict__ b2,
    float* __restrict__ sems)
{
  __shared__ __align__(16) char smem[32768];
  const int bid = blockIdx.x;
  const int tid = threadIdx.x, wid = tid >> 6, lane = tid & 63;
  const int wr = wid >> 1, wc = wid & 1;
  const int lc = lane & 15, hi2 = lane >> 4;
  const int lj = lane >> 4, lc2 = lane & 15;

  if (bid < 512) {
    // ----------------- gates(t): 64 rows x (32 cols x 3 gates) -------------
    // r/z: hi*Bh + lo*Bh (weight-lo dropped, sigmoid-damped);
    // n:   hi*Bh + lo*Bh + hi*Bl (full bf16x3).
    if (t >= H) return;
    const int row0 = (bid & 31) * 64;
    const int gc   = (bid >> 5) * 32;
    char* Ah = smem;             // 8 KB
    char* Al = smem + 8192;      // 8 KB
    char* Bh = smem + 16384;     // 12 KB (96 rows)
    char* Bl = smem + 28672;     // 4 KB  (32 rows, n-gate only)
    f32x4 acc[3][2] = {};

    for (int kt = 0; kt < 8; ++kt) {
      #pragma unroll
      for (int it = 0; it < 2; ++it) {
        int s = it * 256 + tid, pr = s >> 3, pc = s & 7;
        int lch = pc ^ (pr & 7);
        size_t off = (size_t)(row0 + pr) * D + kt * 64 + lch * 8;
        gload_lds16(hbh_in + off, Ah + it * 4096 + wid * 1024);
        gload_lds16(hbl_in + off, Al + it * 4096 + wid * 1024);
      }
      #pragma unroll
      for (int it = 0; it < 3; ++it) {
        int s = it * 256 + tid, pr = s >> 3, pc = s & 7;
        int lch = pc ^ (pr & 7);
        int g = pr >> 5, lr = pr & 31;
        gload_lds16(whh_hi + (size_t)(g * D + gc + lr) * D + kt * 64 + lch * 8,
                    Bh + it * 4096 + wid * 1024);
      }
      { // n-gate weight-lo strip
        int pr = tid >> 3, pc = tid & 7;
        int lch = pc ^ (pr & 7);
        gload_lds16(whh_lo + (size_t)(2 * D + gc + pr) * D + kt * 64 + lch * 8,
                    Bl + wid * 1024);
      }
      asm volatile("s_waitcnt vmcnt(0)" ::: "memory");
      __syncthreads();

      #pragma unroll
      for (int kk = 0; kk < 2; ++kk) {
        int ch = kk * 4 + hi2;
        bf16x8 afh[2], afl[2];
        #pragma unroll
        for (int mi = 0; mi < 2; ++mi) {
          int r = wr * 32 + mi * 16 + lc;
          int o = r * 128 + ((ch ^ (r & 7)) << 4);
          afh[mi] = *(const bf16x8*)(Ah + o);
          afl[mi] = *(const bf16x8*)(Al + o);
        }
        const int rloc = wc * 16 + lc;                 // 0..31 within a gate
        #pragma unroll
        for (int g = 0; g < 3; ++g) {
          int rb = g * 32 + rloc;
          int bo = rb * 128 + ((ch ^ (rb & 7)) << 4);
          bf16x8 bh = *(const bf16x8*)(Bh + bo);
          #pragma unroll
          for (int mi = 0; mi < 2; ++mi) {
            f32x4 a = acc[g][mi];
            a = mfma16(afh[mi], bh, a);
            a = mfma16(afl[mi], bh, a);
            acc[g][mi] = a;
          }
        }
        { // n-gate extra term: hi * weight-lo
          int bo = rloc * 128 + ((ch ^ (rloc & 7)) << 4);
          bf16x8 bl = *(const bf16x8*)(Bl + bo);
          #pragma unroll
          for (int mi = 0; mi < 2; ++mi)
            acc[2][mi] = mfma16(afh[mi], bl, acc[2][mi]);
        }
      }
      __syncthreads();
    }

    const int gcol = gc + wc * 16 + lc2;
    const float br = bhh[gcol];
    const float bz = bhh[512 + gcol];
    const float bn = bhh[1024 + gcol];
    #pragma unroll
    for (int mi = 0; mi < 2; ++mi)
      #pragma unroll
      for (int j = 0; j < 4; ++j) {
        int row = row0 + wr * 32 + mi * 16 + lj * 4 + j;
        size_t g0i = (size_t)row * D3 + gcol;
        float gr = G0[g0i]        + Tg[t * D3 + gcol]        + acc[0][mi][j];
        float gz = G0[g0i + 512]  + Tg[t * D3 + 512 + gcol]  + acc[1][mi][j];
        float gn = G0[g0i + 1024] + Tg[t * D3 + 1024 + gcol];   // inn only
        float r = sigm(gr + br);
        float z = sigm(gz + bz);
        float n = tanhf(gn + r * (acc[2][mi][j] + bn));
        size_t hi_ = (size_t)row * D + gcol;
        float hnew = (1.f - z) * n + z * hf_in[hi_];
        hf_out[hi_] = hnew;
        u16 hh = f2bf(hnew);
        hbh_out[hi_] = hh;
        hbl_out[hi_] = f2bf(hnew - bf2f(hh));
      }
  } else if (bid < 768) {
    // ----------------- hidGEMM(t-2): 64 x 64, A = hb hi only, dbuf ---------
    if (t < 2 || t > H + 1) return;
    const int i = bid - 512;
    const int row0 = (i & 31) * 64, col0 = (i >> 5) * 64;
    char* bufp[2] = { smem, smem + 16384 };   // each: A 8KB + B 8KB
    f32x4 acc[2][2] = {};

    auto stage = [&](char* base, int kt){
      #pragma unroll
      for (int it = 0; it < 2; ++it) {
        int s = it * 256 + tid, pr = s >> 3, pc = s & 7;
        int lch = pc ^ (pr & 7);
        gload_lds16(lbh + (size_t)(row0 + pr) * D + kt * 64 + lch * 8,
                    base + it * 4096 + wid * 1024);
        gload_lds16(W1g + (size_t)(col0 + pr) * D + kt * 64 + lch * 8,
                    base + 8192 + it * 4096 + wid * 1024);
      }
    };

    stage(bufp[0], 0);
    __syncthreads();
    int buf = 0;
    for (int kt = 0; kt < 8; ++kt) {
      if (kt < 7) stage(bufp[buf ^ 1], kt + 1);
      const char* Ah = bufp[buf];
      const char* Bs = bufp[buf] + 8192;
      #pragma unroll
      for (int kk = 0; kk < 2; ++kk) {
        int ch = kk * 4 + hi2;
        bf16x8 afh[2], bf[2];
        #pragma unroll
        for (int mi = 0; mi < 2; ++mi) {
          int r = wr * 32 + mi * 16 + lc;
          afh[mi] = *(const bf16x8*)(Ah + r * 128 + ((ch ^ (r & 7)) << 4));
        }
        #pragma unroll
        for (int ci = 0; ci < 2; ++ci) {
          int r = wc * 32 + ci * 16 + lc;
          bf[ci] = *(const bf16x8*)(Bs + r * 128 + ((ch ^ (r & 7)) << 4));
        }
        #pragma unroll
        for (int mi = 0; mi < 2; ++mi)
          #pragma unroll
          for (int ci = 0; ci < 2; ++ci)
            acc[mi][ci] = mfma16(afh[mi], bf[ci], acc[mi][ci]);
      }
      __syncthreads();
      buf ^= 1;
    }

    #pragma unroll
    for (int mi = 0; mi < 2; ++mi)
      #pragma unroll
      for (int ci = 0; ci < 2; ++ci)
        #pragma unroll
        for (int j = 0; j < 4; ++j) {
          int row = row0 + wr * 32 + mi * 16 + lj * 4 + j;
          int col = col0 + wc * 32 + ci * 16 + lc2;
          float4 st = stats_r[row];   // {rsd1, m1*rsd1, rs2, m2*rs2}
          float hn_w1 = st.x * acc[mi][ci][j] - st.y * d1[col] + d2[col];
          float pre = st.z * (Psem[(size_t)row * D + col] + hn_w1)
                      - st.w * c1[col] + c2p[col];
          float gl = 0.5f * pre * (1.f + erff(pre * 0.70710678118654752f));
          hid_w[(size_t)row * D + col] = f2bf(gl);
        }
  } else if (bid < 1024) {
    // ----------------- sem(t-3): 64 x 64 plain, dbuf -----------------------
    if (t < 3) return;
    const int ts = t - 3;
    const int i = bid - 768;
    const int row0 = (i & 31) * 64, col0 = (i >> 5) * 64;
    char* bufp[2] = { smem, smem + 16384 };
    f32x4 acc[2][2] = {};

    auto stage = [&](char* base, int kt){
      #pragma unroll
      for (int it = 0; it < 2; ++it) {
        int s = it * 256 + tid, pr = s >> 3, pc = s & 7;
        int lch = pc ^ (pr & 7);
        gload_lds16(hid_r + (size_t)(row0 + pr) * D + kt * 64 + lch * 8,
                    base + it * 4096 + wid * 1024);
        gload_lds16(w2bf + (size_t)(col0 + pr) * D + kt * 64 + lch * 8,
                    base + 8192 + it * 4096 + wid * 1024);
      }
    };

    stage(bufp[0], 0);
    __syncthreads();
    int buf = 0;
    for (int kt = 0; kt < 8; ++kt) {
      if (kt < 7) stage(bufp[buf ^ 1], kt + 1);
      const char* As = bufp[buf];
      const char* Bs = bufp[buf] + 8192;
      #pragma unroll
      for (int kk = 0; kk < 2; ++kk) {
        int ch = kk * 4 + hi2;
        bf16x8 af[2], bf[2];
        #pragma unroll
        for (int mi = 0; mi < 2; ++mi) {
          int r = wr * 32 + mi * 16 + lc;
          af[mi] = *(const bf16x8*)(As + r * 128 + ((ch ^ (r & 7)) << 4));
        }
        #pragma unroll
        for (int ci = 0; ci < 2; ++ci) {
          int r = wc * 32 + ci * 16 + lc;
          bf[ci] = *(const bf16x8*)(Bs + r * 128 + ((ch ^ (r & 7)) << 4));
        }
        #pragma unroll
        for (int mi = 0; mi < 2; ++mi)
          #pragma unroll
          for (int ci = 0; ci < 2; ++ci)
            acc[mi][ci] = mfma16(af[mi], bf[ci], acc[mi][ci]);
      }
      __syncthreads();
      buf ^= 1;
    }

    #pragma unroll
    for (int mi = 0; mi < 2; ++mi)
      #pragma unroll
      for (int ci = 0; ci < 2; ++ci)
        #pragma unroll
        for (int j = 0; j < 4; ++j) {
          int row = row0 + wr * 32 + mi * 16 + lj * 4 + j;
          int col = col0 + wc * 32 + ci * 16 + lc2;
          float v = zsem[(size_t)row * D + col] + acc[mi][ci][j] + b2[col];
          __builtin_nontemporal_store(
              v, &sems[((size_t)row * H + ts) * D + col]);
        }
  } else {
    // ----------------- stats(t-1) + dyn(t-1): 16 rows/block, fp32 h --------
    if (t < 1 || t > H) return;
    const int tt = t - 1;
    const int base = (bid - 1024) * 16 + wid * 4;
    const float4 g0 = *(const float4*)(ln_g + lane * 8);
    const float4 g1 = *(const float4*)(ln_g + lane * 8 + 4);
    const float4 b0 = *(const float4*)(ln_b + lane * 8);
    const float4 b1v = *(const float4*)(ln_b + lane * 8 + 4);
    const float gg[8] = {g0.x,g0.y,g0.z,g0.w,g1.x,g1.y,g1.z,g1.w};
    const float bb[8] = {b0.x,b0.y,b0.z,b0.w,b1v.x,b1v.y,b1v.z,b1v.w};

    for (int rr = 0; rr < 4; ++rr) {
      const int row = base + rr;
      const float* hp = hf_in + (size_t)row * D + lane * 8;
      float4 a0 = *(const float4*)hp, a1 = *(const float4*)(hp + 4);
      float h[8] = {a0.x, a0.y, a0.z, a0.w, a1.x, a1.y, a1.z, a1.w};
      float s1 = 0.f;
      #pragma unroll
      for (int k = 0; k < 8; ++k) s1 += h[k];
      #pragma unroll
      for (int o = 1; o < 64; o <<= 1) s1 += __shfl_xor(s1, o);
      float m1 = s1 * (1.f / 512.f);
      float s2 = 0.f;
      #pragma unroll
      for (int k = 0; k < 8; ++k) {
        float dv = h[k] - m1;
        s2 += dv * dv;
      }
      #pragma unroll
      for (int o = 1; o < 64; o <<= 1) s2 += __shfl_xor(s2, o);
      float rsd1 = rsqrtf(s2 * (1.f / 512.f) + 1e-5f);

      float hn[8];
      float sh = 0.f, sh2 = 0.f;
      #pragma unroll
      for (int k = 0; k < 8; ++k) {
        float x = (h[k] - m1) * rsd1 * gg[k] + bb[k];
        hn[k] = x; sh += x; sh2 += x * x;
      }
      float* dp = dyn + ((size_t)row * H + tt) * D + lane * 8;
      f32x4 v0 = {hn[0], hn[1], hn[2], hn[3]};
      f32x4 v1 = {hn[4], hn[5], hn[6], hn[7]};
      __builtin_nontemporal_store(v0, (f32x4*)dp);
      __builtin_nontemporal_store(v1, (f32x4*)(dp + 4));

      #pragma unroll
      for (int o = 1; o < 64; o <<= 1) {
        sh += __shfl_xor(sh, o); sh2 += __shfl_xor(sh2, o);
      }
      if (lane == 0) {
        float m2 = (Ssem[row] + sh) * (1.f / 1024.f);
        float vv = (Ssem2[row] + sh2) * (1.f / 1024.f) - m2 * m2;
        float rs2 = rsqrtf(vv + 1e-5f);
        stats_w[row] = make_float4(rsd1, m1 * rsd1, rs2, m2 * rs2);
      }
    }
  }
}

// ---------------------------------------------------------------------------
extern "C" void kernel_launch(void* const* d_in, const int* in_sizes, int n_in,
                              void* d_out, int out_size, void* d_ws, size_t ws_size,
                              hipStream_t stream)
{
  (void)in_sizes; (void)n_in; (void)out_size; (void)ws_size;
  const float* z_dyn = (const float*)d_in[0];
  const float* z_sem = (const float*)d_in[1];
  const float* te_w  = (const float*)d_in[2];
  const float* w_ih  = (const float*)d_in[3];
  const float* w_hh  = (const float*)d_in[4];
  const float* b_ih  = (const float*)d_in[5];
  const float* b_hh  = (const float*)d_in[6];
  const float* ln_g  = (const float*)d_in[7];
  const float* ln_b  = (const float*)d_in[8];
  const float* ln2_g = (const float*)d_in[9];
  const float* ln2_b = (const float*)d_in[10];
  const float* w1    = (const float*)d_in[11];
  const float* b1    = (const float*)d_in[12];
  const float* w2    = (const float*)d_in[13];
  const float* b2    = (const float*)d_in[14];

  char* ws = (char*)d_ws;
  const size_t MB = 1ull << 20;
  u16* hbh[3] = { (u16*)(ws + 0),      (u16*)(ws + 2 * MB),  (u16*)(ws + 4 * MB) };
  u16* hbl[3] = { (u16*)(ws + 6 * MB), (u16*)(ws + 8 * MB),  (u16*)(ws + 10 * MB) };
  float* G0     = (float*)(ws + 12 * MB);            // 12 MB
  float* Psem   = (float*)(ws + 25 * MB);            // 4 MB
  u16*  sem_hi  = (u16*)(ws + 29 * MB);              // 2 MB
  u16*  sem_lo  = (u16*)(ws + 31 * MB);              // 2 MB
  u16*  hid0    = (u16*)(ws + 33 * MB);              // 2 MB
  u16*  hid1    = (u16*)(ws + 35 * MB);              // 2 MB
  u16*  wih_hi  = (u16*)(ws + 37 * MB);              // 1.5 MB
  u16*  wih_lo  = (u16*)(ws + 37 * MB + 1572864);    // 1.5 MB
  u16*  whh_hi  = (u16*)(ws + 40 * MB);              // 1.5 MB
  u16*  whh_lo  = (u16*)(ws + 40 * MB + 1572864);    // 1.5 MB
  u16*  W1s     = (u16*)(ws + 43 * MB);              // 512 KB
  u16*  W1g     = (u16*)(ws + 43 * MB + 524288);     // 512 KB
  u16*  w2bf    = (u16*)(ws + 44 * MB);              // 512 KB
  float* c1     = (float*)(ws + 45 * MB);
  float* c2p    = (float*)(ws + 45 * MB + 16384);
  float* d1     = (float*)(ws + 45 * MB + 32768);
  float* d2     = (float*)(ws + 45 * MB + 49152);
  float* Ssem   = (float*)(ws + 45 * MB + 65536);
  float* Ssem2  = (float*)(ws + 45 * MB + 81920);
  float4* stats0 = (float4*)(ws + 46 * MB);          // 32 KB
  float4* stats1 = (float4*)(ws + 46 * MB + 32768);  // 32 KB
  float* Tg     = (float*)(ws + 47 * MB);            // 192 KB
  float* hf0    = (float*)(ws + 48 * MB);            // 4 MB
  float* hf1    = (float*)(ws + 52 * MB);            // 4 MB

  float* outp = (float*)d_out;
  float* out_dyn  = outp;
  float* out_sems = outp + OUT_HALF;

  // initial state h(-1): hb slot 2 (== (-1) mod 3), hf slot 1 (== (-1) & 1)
  prep_kernel<<<4096, 256, 0, stream>>>(
      z_dyn, z_sem, te_w, w_ih, w_hh, ln_g, ln_b, ln2_g, ln2_b, w1, b1, w2,
      hf1, hbh[2], hbl[2], sem_hi, sem_lo, wih_hi, wih_lo, whh_hi, whh_lo,
      W1s, W1g, w2bf, c1, c2p, d1, d2, Tg);
  rowstats_kernel<<<512, 256, 0, stream>>>(z_sem, Ssem, Ssem2);
  setup_kernel<<<dim3(32, 32), 256, 0, stream>>>(
      sem_hi, sem_lo, wih_hi, wih_lo, W1s, G0, Psem, b_ih);

  for (int t = 0; t <= H + 2; ++t) {
    int s_out  = ((t % 3) + 3) % 3;          // gates write hb slot(t)
    int s_in   = (((t - 1) % 3) + 3) % 3;    // gates read hb slot(t-1)
    int s_ln   = (((t - 2) % 3) + 3) % 3;    // hidGEMM reads hb slot(t-2)
    float* hf_out      = (t & 1) ? hf1 : hf0;
    const float* hf_in = (t & 1) ? hf0 : hf1;   // slot (t-1)&1
    float4* st_w = ((t - 1) & 1) ? stats1 : stats0;
    const float4* st_r = ((t - 2) & 1) ? stats1 : stats0;
    u16* hidw = ((t - 2) & 1) ? hid1 : hid0;
    const u16* hidr = ((t - 3) & 1) ? hid1 : hid0;

    fused_kernel<<<dim3(1152), dim3(256), 0, stream>>>(
        t,
        hbh[s_in], hbl[s_in], hbh[s_out], hbl[s_out],
        hf_in, hf_out,
        whh_hi, whh_lo, G0, Tg, b_hh,
        st_w, out_dyn, ln_g, ln_b, Ssem, Ssem2,
        hbh[s_ln], st_r, W1g, Psem, d1, d2, c1, c2p, hidw,
        hidr, w2bf, z_sem, b2, out_sems);
  }
}

// Round 12
// 722.370 us; speedup vs baseline: 1.8223x; 1.0237x over previous
//
#include <hip/hip_runtime.h>
#include <math.h>

// ---------------------------------------------------------------------------
// TemporalUnitRolloutV341 — GRU rollout, 32 steps over 2048 rows of D=512.
// R12 = R11 (one dispatch/step, 4 concurrent block ranges, LN1 hoisted,
// bf16x3-where-needed, dbuf hid/sem) +
//   (1) issue-early epilogue preloads (G0/hf in gates, Psem/stats in hid,
//       zsem in sem) — L2 latency hides under the K-loop (T14 pattern)
//   (2) fast transcendentals (__expf-based sigm/tanh; ~1e-7 abs err)
//   (3) prep c1/d1/W1g loop wave-parallelized (was a 512-iter serial
//       straggler on 2 blocks with uncoalesced w1 reads)
// ---------------------------------------------------------------------------

typedef unsigned short u16;
using bf16x8 = __attribute__((ext_vector_type(8))) short;
using f32x4  = __attribute__((ext_vector_type(4))) float;

#define DEV __device__ __forceinline__

constexpr int D   = 512;
constexpr int D3  = 1536;
constexpr int H   = 32;
constexpr int BU  = 2048;
constexpr long long OUT_HALF = (long long)BU * H * D;

DEV u16 f2bf(float x){
  union { float f; unsigned u; } c; c.f = x;
  unsigned u = c.u;
  u += 0x7fffu + ((u >> 16) & 1u);
  return (u16)(u >> 16);
}
DEV float bf2f(u16 b){
  union { unsigned u; float f; } c; c.u = ((unsigned)b) << 16; return c.f;
}

DEV void gload_lds16(const void* g, void* l){
  __builtin_amdgcn_global_load_lds(
      (const __attribute__((address_space(1))) void*)g,
      (__attribute__((address_space(3))) void*)l, 16, 0, 0);
}

DEV f32x4 mfma16(bf16x8 a, bf16x8 b, f32x4 c){
  return __builtin_amdgcn_mfma_f32_16x16x32_bf16(a, b, c, 0, 0, 0);
}

DEV float fsigm(float x){ return 1.f / (1.f + __expf(-x)); }
DEV float ftanh(float x){ return 1.f - 2.f / (1.f + __expf(2.f * x)); }

// ---------------------------------------------------------------------------
// prep: hi/lo splits, W1s, W1g, c1/c2p/d1/d2, Tg, initial state.
// ---------------------------------------------------------------------------
__global__ __launch_bounds__(256) void prep_kernel(
    const float* __restrict__ z_dyn, const float* __restrict__ z_sem,
    const float* __restrict__ te_w,  const float* __restrict__ w_ih,
    const float* __restrict__ w_hh,  const float* __restrict__ ln_g,
    const float* __restrict__ ln_b,  const float* __restrict__ ln2_g,
    const float* __restrict__ ln2_b, const float* __restrict__ w1,
    const float* __restrict__ b1,    const float* __restrict__ w2,
    float* __restrict__ h1, u16* __restrict__ hbh2, u16* __restrict__ hbl2,
    u16* __restrict__ sem_hi, u16* __restrict__ sem_lo,
    u16* __restrict__ wih_hi, u16* __restrict__ wih_lo,
    u16* __restrict__ whh_hi, u16* __restrict__ whh_lo,
    u16* __restrict__ W1s, u16* __restrict__ W1g, u16* __restrict__ w2bf,
    float* __restrict__ c1, float* __restrict__ c2p,
    float* __restrict__ d1, float* __restrict__ d2, float* __restrict__ Tg)
{
  int i = blockIdx.x * 256 + threadIdx.x;
  if (i < BU * D) {
    float hv = z_dyn[i];
    h1[i] = hv;
    u16 hh = f2bf(hv);
    hbh2[i] = hh;
    hbl2[i] = f2bf(hv - bf2f(hh));
    float sv = z_sem[i];
    u16 sh_ = f2bf(sv);
    sem_hi[i] = sh_;
    sem_lo[i] = f2bf(sv - bf2f(sh_));
  }
  if (i < D3 * D) {
    float wv = w_ih[i];
    u16 wh = f2bf(wv);
    wih_hi[i] = wh;
    wih_lo[i] = f2bf(wv - bf2f(wh));
    float uv = w_hh[i];
    u16 uh = f2bf(uv);
    whh_hi[i] = uh;
    whh_lo[i] = f2bf(uv - bf2f(uh));
  }
  if (i < D * D) {
    int k = i >> 9, j = i & 511;
    W1s[i]  = f2bf(w1[k * 1024 + j] * ln2_g[j]);
    w2bf[i] = f2bf(w2[i]);
  }
  if (i < D * 64) {
    // one wave per output row r: coalesced w1 reads, shfl reduce
    int r = i >> 6, ln = i & 63;
    float sc1 = 0.f, sc2 = 0.f, sd1 = 0.f, sd2 = 0.f;
    #pragma unroll
    for (int jj = 0; jj < 8; ++jj) {
      int j = jj * 64 + ln;
      float wA = w1[r * 1024 + j];
      float wB = w1[r * 1024 + 512 + j];
      sc1 += wA * ln2_g[j] + wB * ln2_g[512 + j];
      sc2 += wA * ln2_b[j] + wB * ln2_b[512 + j];
      float wBg = wB * ln2_g[512 + j];          // = W1h[r][j]
      float wg = wBg * ln_g[j];                 // = W1g[r][j]
      sd1 += wg;
      sd2 += wBg * ln_b[j];
      W1g[r * 512 + j] = f2bf(wg);
    }
    #pragma unroll
    for (int o = 1; o < 64; o <<= 1) {
      sc1 += __shfl_xor(sc1, o); sc2 += __shfl_xor(sc2, o);
      sd1 += __shfl_xor(sd1, o); sd2 += __shfl_xor(sd2, o);
    }
    if (ln == 0) {
      c1[r] = sc1;
      c2p[r] = sc2 + b1[r];
      d1[r] = sd1;
      d2[r] = sd2;
    }
  }
  if (i < H * D3) {
    // broadcast-friendly: 32 lanes share one w_ih row (uniform load)
    int c = i >> 5, t = i & 31;
    float s = 0.f;
    for (int d0 = 0; d0 < D; ++d0) s += te_w[t * D + d0] * w_ih[c * D + d0];
    Tg[t * D3 + c] = s;
  }
}

// Per-row sums of sem and sem^2 (ln2 stats split). One wave per row.
__global__ __launch_bounds__(256) void rowstats_kernel(
    const float* __restrict__ sem, float* __restrict__ Ssem,
    float* __restrict__ Ssem2)
{
  const int wid = threadIdx.x >> 6, lane = threadIdx.x & 63;
  const int row = blockIdx.x * 4 + wid;
  const float* p = sem + (size_t)row * D + lane * 8;
  float4 a0 = *(const float4*)p;
  float4 a1 = *(const float4*)(p + 4);
  float s  = a0.x + a0.y + a0.z + a0.w + a1.x + a1.y + a1.z + a1.w;
  float s2 = a0.x*a0.x + a0.y*a0.y + a0.z*a0.z + a0.w*a0.w
           + a1.x*a1.x + a1.y*a1.y + a1.z*a1.z + a1.w*a1.w;
  #pragma unroll
  for (int o = 1; o < 64; o <<= 1) { s += __shfl_xor(s, o); s2 += __shfl_xor(s2, o); }
  if (lane == 0) { Ssem[row] = s; Ssem2[row] = s2; }
}

// ---------------------------------------------------------------------------
// Setup GEMMs: grid (32, 32). by<24 -> G0 tile (bf16x3, +b_ih);
// by>=24 -> Psem tile (plain bf16). 64x64 NT, single-buffered 32KB LDS.
// ---------------------------------------------------------------------------
__global__ __launch_bounds__(256) void setup_kernel(
    const u16* __restrict__ sem_hi, const u16* __restrict__ sem_lo,
    const u16* __restrict__ wih_hi, const u16* __restrict__ wih_lo,
    const u16* __restrict__ W1s, float* __restrict__ G0,
    float* __restrict__ Psem, const float* __restrict__ b_ih)
{
  __shared__ __align__(16) char smem[32768];
  char* Ah = smem;
  char* Al = smem + 8192;
  char* Bh = smem + 16384;
  char* Bl = smem + 24576;
  const int tid = threadIdx.x, wid = tid >> 6, lane = tid & 63;
  const int wr = wid >> 1, wc = wid & 1;
  const bool isG0 = blockIdx.y < 24;
  const u16* Bsrc = isG0 ? wih_hi : W1s;
  const int row0 = blockIdx.x * 64;
  const int col0 = (isG0 ? blockIdx.y : blockIdx.y - 24) * 64;

  f32x4 acc[2][2] = {};
  for (int kt = 0; kt < 8; ++kt) {
    #pragma unroll
    for (int it = 0; it < 2; ++it) {
      int s = it * 256 + tid, pr = s >> 3, pc = s & 7;
      int lch = pc ^ (pr & 7);
      size_t aoff = (size_t)(row0 + pr) * D + kt * 64 + lch * 8;
      size_t boff = (size_t)(col0 + pr) * D + kt * 64 + lch * 8;
      gload_lds16(sem_hi + aoff, Ah + it * 4096 + wid * 1024);
      gload_lds16(Bsrc + boff,   Bh + it * 4096 + wid * 1024);
      if (isG0) {
        gload_lds16(sem_lo + aoff, Al + it * 4096 + wid * 1024);
        gload_lds16(wih_lo + boff, Bl + it * 4096 + wid * 1024);
      }
    }
    asm volatile("s_waitcnt vmcnt(0)" ::: "memory");
    __syncthreads();

    const int lc = lane & 15, hi2 = lane >> 4;
    #pragma unroll
    for (int kk = 0; kk < 2; ++kk) {
      int ch = kk * 4 + hi2;
      bf16x8 afh[2], afl[2], bfh[2], bfl[2];
      #pragma unroll
      for (int mi = 0; mi < 2; ++mi) {
        int r = wr * 32 + mi * 16 + lc;
        int o = r * 128 + ((ch ^ (r & 7)) << 4);
        afh[mi] = *(const bf16x8*)(Ah + o);
        if (isG0) afl[mi] = *(const bf16x8*)(Al + o);
      }
      #pragma unroll
      for (int ci = 0; ci < 2; ++ci) {
        int r = wc * 32 + ci * 16 + lc;
        int o = r * 128 + ((ch ^ (r & 7)) << 4);
        bfh[ci] = *(const bf16x8*)(Bh + o);
        if (isG0) bfl[ci] = *(const bf16x8*)(Bl + o);
      }
      #pragma unroll
      for (int mi = 0; mi < 2; ++mi)
        #pragma unroll
        for (int ci = 0; ci < 2; ++ci) {
          f32x4 a = acc[mi][ci];
          a = mfma16(afh[mi], bfh[ci], a);
          if (isG0) {
            a = mfma16(afl[mi], bfh[ci], a);
            a = mfma16(afh[mi], bfl[ci], a);
          }
          acc[mi][ci] = a;
        }
    }
    __syncthreads();
  }
  const int lj = lane >> 4, lc2 = lane & 15;
  #pragma unroll
  for (int mi = 0; mi < 2; ++mi)
    #pragma unroll
    for (int ci = 0; ci < 2; ++ci)
      #pragma unroll
      for (int j = 0; j < 4; ++j) {
        int row = row0 + wr * 32 + mi * 16 + lj * 4 + j;
        int col = col0 + wc * 32 + ci * 16 + lc2;
        float v = acc[mi][ci][j];
        if (isG0) G0[(size_t)row * D3 + col] = v + b_ih[col];
        else      Psem[(size_t)row * D + col] = v;
      }
}

// ---------------------------------------------------------------------------
// Fused step dispatch: 1152 blocks, 4 concurrent ranges.
//   [0,512):    gates(t)      (t<32)  64r x 32c x 3g; r/z bf16x2, n bf16x3
//   [512,768):  hidGEMM(t-2)           64x64, A=hb hi only, B=W1g, dbuf
//   [768,1024): sem(t-3)               64x64 plain, dbuf
//   [1024,1152):stats(t-1)+dyn         16 rows/block, fp32 h, two-pass
// ---------------------------------------------------------------------------
__global__ __launch_bounds__(256, 4) void fused_kernel(
    int t,
    // gates
    const u16* __restrict__ hbh_in, const u16* __restrict__ hbl_in,
    u16* __restrict__ hbh_out, u16* __restrict__ hbl_out,
    const float* __restrict__ hf_in, float* __restrict__ hf_out,
    const u16* __restrict__ whh_hi, const u16* __restrict__ whh_lo,
    const float* __restrict__ G0, const float* __restrict__ Tg,
    const float* __restrict__ bhh,
    // stats(t-1): reads hf_in (slot t-1)
    float4* __restrict__ stats_w, float* __restrict__ dyn,
    const float* __restrict__ ln_g, const float* __restrict__ ln_b,
    const float* __restrict__ Ssem, const float* __restrict__ Ssem2,
    // hidGEMM(t-2)
    const u16* __restrict__ lbh,
    const float4* __restrict__ stats_r, const u16* __restrict__ W1g,
    const float* __restrict__ Psem, const float* __restrict__ d1,
    const float* __restrict__ d2, const float* __restrict__ c1,
    const float* __restrict__ c2p, u16* __restrict__ hid_w,
    // sem(t-3)
    const u16* __restrict__ hid_r, const u16* __restrict__ w2bf,
    const float* __restrict__ zsem, const float* __restrict__ b2,
    float* __restrict__ sems)
{
  __shared__ __align__(16) char smem[32768];
  const int bid = blockIdx.x;
  const int tid = threadIdx.x, wid = tid >> 6, lane = tid & 63;
  const int wr = wid >> 1, wc = wid & 1;
  const int lc = lane & 15, hi2 = lane >> 4;
  const int lj = lane >> 4, lc2 = lane & 15;

  if (bid < 512) {
    // ----------------- gates(t): 64 rows x (32 cols x 3 gates) -------------
    if (t >= H) return;
    const int row0 = (bid & 31) * 64;
    const int gc   = (bid >> 5) * 32;
    char* Ah = smem;             // 8 KB
    char* Al = smem + 8192;      // 8 KB
    char* Bh = smem + 16384;     // 12 KB (96 rows)
    char* Bl = smem + 28672;     // 4 KB  (32 rows, n-gate only)
    f32x4 acc[3][2] = {};

    const int gcol = gc + wc * 16 + lc2;

    // issue-early epilogue operand preloads: latency hides under K-loop
    float pre_gr[2][4], pre_gz[2][4], pre_gn[2][4], pre_hf[2][4];
    #pragma unroll
    for (int mi = 0; mi < 2; ++mi)
      #pragma unroll
      for (int j = 0; j < 4; ++j) {
        int row = row0 + wr * 32 + mi * 16 + lj * 4 + j;
        size_t g0i = (size_t)row * D3 + gcol;
        pre_gr[mi][j] = G0[g0i];
        pre_gz[mi][j] = G0[g0i + 512];
        pre_gn[mi][j] = G0[g0i + 1024];
        pre_hf[mi][j] = hf_in[(size_t)row * D + gcol];
      }

    for (int kt = 0; kt < 8; ++kt) {
      #pragma unroll
      for (int it = 0; it < 2; ++it) {
        int s = it * 256 + tid, pr = s >> 3, pc = s & 7;
        int lch = pc ^ (pr & 7);
        size_t off = (size_t)(row0 + pr) * D + kt * 64 + lch * 8;
        gload_lds16(hbh_in + off, Ah + it * 4096 + wid * 1024);
        gload_lds16(hbl_in + off, Al + it * 4096 + wid * 1024);
      }
      #pragma unroll
      for (int it = 0; it < 3; ++it) {
        int s = it * 256 + tid, pr = s >> 3, pc = s & 7;
        int lch = pc ^ (pr & 7);
        int g = pr >> 5, lr = pr & 31;
        gload_lds16(whh_hi + (size_t)(g * D + gc + lr) * D + kt * 64 + lch * 8,
                    Bh + it * 4096 + wid * 1024);
      }
      { // n-gate weight-lo strip
        int pr = tid >> 3, pc = tid & 7;
        int lch = pc ^ (pr & 7);
        gload_lds16(whh_lo + (size_t)(2 * D + gc + pr) * D + kt * 64 + lch * 8,
                    Bl + wid * 1024);
      }
      asm volatile("s_waitcnt vmcnt(0)" ::: "memory");
      __syncthreads();

      #pragma unroll
      for (int kk = 0; kk < 2; ++kk) {
        int ch = kk * 4 + hi2;
        bf16x8 afh[2], afl[2];
        #pragma unroll
        for (int mi = 0; mi < 2; ++mi) {
          int r = wr * 32 + mi * 16 + lc;
          int o = r * 128 + ((ch ^ (r & 7)) << 4);
          afh[mi] = *(const bf16x8*)(Ah + o);
          afl[mi] = *(const bf16x8*)(Al + o);
        }
        const int rloc = wc * 16 + lc;                 // 0..31 within a gate
        #pragma unroll
        for (int g = 0; g < 3; ++g) {
          int rb = g * 32 + rloc;
          int bo = rb * 128 + ((ch ^ (rb & 7)) << 4);
          bf16x8 bh = *(const bf16x8*)(Bh + bo);
          #pragma unroll
          for (int mi = 0; mi < 2; ++mi) {
            f32x4 a = acc[g][mi];
            a = mfma16(afh[mi], bh, a);
            a = mfma16(afl[mi], bh, a);
            acc[g][mi] = a;
          }
        }
        { // n-gate extra term: hi * weight-lo
          int bo = rloc * 128 + ((ch ^ (rloc & 7)) << 4);
          bf16x8 bl = *(const bf16x8*)(Bl + bo);
          #pragma unroll
          for (int mi = 0; mi < 2; ++mi)
            acc[2][mi] = mfma16(afh[mi], bl, acc[2][mi]);
        }
      }
      __syncthreads();
    }

    const float br = bhh[gcol];
    const float bz = bhh[512 + gcol];
    const float bn = bhh[1024 + gcol];
    const float tr = Tg[t * D3 + gcol];
    const float tz = Tg[t * D3 + 512 + gcol];
    const float tn = Tg[t * D3 + 1024 + gcol];
    #pragma unroll
    for (int mi = 0; mi < 2; ++mi)
      #pragma unroll
      for (int j = 0; j < 4; ++j) {
        int row = row0 + wr * 32 + mi * 16 + lj * 4 + j;
        float gr = pre_gr[mi][j] + tr + acc[0][mi][j];
        float gz = pre_gz[mi][j] + tz + acc[1][mi][j];
        float gn = pre_gn[mi][j] + tn;                 // inn only
        float r = fsigm(gr + br);
        float z = fsigm(gz + bz);
        float n = ftanh(gn + r * (acc[2][mi][j] + bn));
        size_t hi_ = (size_t)row * D + gcol;
        float hnew = (1.f - z) * n + z * pre_hf[mi][j];
        hf_out[hi_] = hnew;
        u16 hh = f2bf(hnew);
        hbh_out[hi_] = hh;
        hbl_out[hi_] = f2bf(hnew - bf2f(hh));
      }
  } else if (bid < 768) {
    // ----------------- hidGEMM(t-2): 64 x 64, A = hb hi only, dbuf ---------
    if (t < 2 || t > H + 1) return;
    const int i = bid - 512;
    const int row0 = (i & 31) * 64, col0 = (i >> 5) * 64;
    char* bufp[2] = { smem, smem + 16384 };   // each: A 8KB + B 8KB
    f32x4 acc[2][2] = {};

    // issue-early epilogue preloads
    float pre_ps[2][2][4];
    float4 pre_st[2][4];
    #pragma unroll
    for (int mi = 0; mi < 2; ++mi)
      #pragma unroll
      for (int j = 0; j < 4; ++j) {
        int row = row0 + wr * 32 + mi * 16 + lj * 4 + j;
        pre_st[mi][j] = stats_r[row];
        #pragma unroll
        for (int ci = 0; ci < 2; ++ci) {
          int col = col0 + wc * 32 + ci * 16 + lc2;
          pre_ps[mi][ci][j] = Psem[(size_t)row * D + col];
        }
      }

    auto stage = [&](char* base, int kt){
      #pragma unroll
      for (int it = 0; it < 2; ++it) {
        int s = it * 256 + tid, pr = s >> 3, pc = s & 7;
        int lch = pc ^ (pr & 7);
        gload_lds16(lbh + (size_t)(row0 + pr) * D + kt * 64 + lch * 8,
                    base + it * 4096 + wid * 1024);
        gload_lds16(W1g + (size_t)(col0 + pr) * D + kt * 64 + lch * 8,
                    base + 8192 + it * 4096 + wid * 1024);
      }
    };

    stage(bufp[0], 0);
    __syncthreads();
    int buf = 0;
    for (int kt = 0; kt < 8; ++kt) {
      if (kt < 7) stage(bufp[buf ^ 1], kt + 1);
      const char* Ah = bufp[buf];
      const char* Bs = bufp[buf] + 8192;
      #pragma unroll
      for (int kk = 0; kk < 2; ++kk) {
        int ch = kk * 4 + hi2;
        bf16x8 afh[2], bf[2];
        #pragma unroll
        for (int mi = 0; mi < 2; ++mi) {
          int r = wr * 32 + mi * 16 + lc;
          afh[mi] = *(const bf16x8*)(Ah + r * 128 + ((ch ^ (r & 7)) << 4));
        }
        #pragma unroll
        for (int ci = 0; ci < 2; ++ci) {
          int r = wc * 32 + ci * 16 + lc;
          bf[ci] = *(const bf16x8*)(Bs + r * 128 + ((ch ^ (r & 7)) << 4));
        }
        #pragma unroll
        for (int mi = 0; mi < 2; ++mi)
          #pragma unroll
          for (int ci = 0; ci < 2; ++ci)
            acc[mi][ci] = mfma16(afh[mi], bf[ci], acc[mi][ci]);
      }
      __syncthreads();
      buf ^= 1;
    }

    #pragma unroll
    for (int mi = 0; mi < 2; ++mi)
      #pragma unroll
      for (int ci = 0; ci < 2; ++ci)
        #pragma unroll
        for (int j = 0; j < 4; ++j) {
          int row = row0 + wr * 32 + mi * 16 + lj * 4 + j;
          int col = col0 + wc * 32 + ci * 16 + lc2;
          float4 st = pre_st[mi][j];   // {rsd1, m1*rsd1, rs2, m2*rs2}
          float hn_w1 = st.x * acc[mi][ci][j] - st.y * d1[col] + d2[col];
          float pre = st.z * (pre_ps[mi][ci][j] + hn_w1)
                      - st.w * c1[col] + c2p[col];
          float gl = 0.5f * pre * (1.f + erff(pre * 0.70710678118654752f));
          hid_w[(size_t)row * D + col] = f2bf(gl);
        }
  } else if (bid < 1024) {
    // ----------------- sem(t-3): 64 x 64 plain, dbuf -----------------------
    if (t < 3) return;
    const int ts = t - 3;
    const int i = bid - 768;
    const int row0 = (i & 31) * 64, col0 = (i >> 5) * 64;
    char* bufp[2] = { smem, smem + 16384 };
    f32x4 acc[2][2] = {};

    // issue-early epilogue preloads
    float pre_zs[2][2][4];
    #pragma unroll
    for (int mi = 0; mi < 2; ++mi)
      #pragma unroll
      for (int ci = 0; ci < 2; ++ci)
        #pragma unroll
        for (int j = 0; j < 4; ++j) {
          int row = row0 + wr * 32 + mi * 16 + lj * 4 + j;
          int col = col0 + wc * 32 + ci * 16 + lc2;
          pre_zs[mi][ci][j] = zsem[(size_t)row * D + col];
        }

    auto stage = [&](char* base, int kt){
      #pragma unroll
      for (int it = 0; it < 2; ++it) {
        int s = it * 256 + tid, pr = s >> 3, pc = s & 7;
        int lch = pc ^ (pr & 7);
        gload_lds16(hid_r + (size_t)(row0 + pr) * D + kt * 64 + lch * 8,
                    base + it * 4096 + wid * 1024);
        gload_lds16(w2bf + (size_t)(col0 + pr) * D + kt * 64 + lch * 8,
                    base + 8192 + it * 4096 + wid * 1024);
      }
    };

    stage(bufp[0], 0);
    __syncthreads();
    int buf = 0;
    for (int kt = 0; kt < 8; ++kt) {
      if (kt < 7) stage(bufp[buf ^ 1], kt + 1);
      const char* As = bufp[buf];
      const char* Bs = bufp[buf] + 8192;
      #pragma unroll
      for (int kk = 0; kk < 2; ++kk) {
        int ch = kk * 4 + hi2;
        bf16x8 af[2], bf[2];
        #pragma unroll
        for (int mi = 0; mi < 2; ++mi) {
          int r = wr * 32 + mi * 16 + lc;
          af[mi] = *(const bf16x8*)(As + r * 128 + ((ch ^ (r & 7)) << 4));
        }
        #pragma unroll
        for (int ci = 0; ci < 2; ++ci) {
          int r = wc * 32 + ci * 16 + lc;
          bf[ci] = *(const bf16x8*)(Bs + r * 128 + ((ch ^ (r & 7)) << 4));
        }
        #pragma unroll
        for (int mi = 0; mi < 2; ++mi)
          #pragma unroll
          for (int ci = 0; ci < 2; ++ci)
            acc[mi][ci] = mfma16(af[mi], bf[ci], acc[mi][ci]);
      }
      __syncthreads();
      buf ^= 1;
    }

    #pragma unroll
    for (int mi = 0; mi < 2; ++mi)
      #pragma unroll
      for (int ci = 0; ci < 2; ++ci)
        #pragma unroll
        for (int j = 0; j < 4; ++j) {
          int row = row0 + wr * 32 + mi * 16 + lj * 4 + j;
          int col = col0 + wc * 32 + ci * 16 + lc2;
          float v = pre_zs[mi][ci][j] + acc[mi][ci][j] + b2[col];
          __builtin_nontemporal_store(
              v, &sems[((size_t)row * H + ts) * D + col]);
        }
  } else {
    // ----------------- stats(t-1) + dyn(t-1): 16 rows/block, fp32 h --------
    if (t < 1 || t > H) return;
    const int tt = t - 1;
    const int base = (bid - 1024) * 16 + wid * 4;
    const float4 g0 = *(const float4*)(ln_g + lane * 8);
    const float4 g1 = *(const float4*)(ln_g + lane * 8 + 4);
    const float4 b0 = *(const float4*)(ln_b + lane * 8);
    const float4 b1v = *(const float4*)(ln_b + lane * 8 + 4);
    const float gg[8] = {g0.x,g0.y,g0.z,g0.w,g1.x,g1.y,g1.z,g1.w};
    const float bb[8] = {b0.x,b0.y,b0.z,b0.w,b1v.x,b1v.y,b1v.z,b1v.w};

    for (int rr = 0; rr < 4; ++rr) {
      const int row = base + rr;
      const float* hp = hf_in + (size_t)row * D + lane * 8;
      float4 a0 = *(const float4*)hp, a1 = *(const float4*)(hp + 4);
      float h[8] = {a0.x, a0.y, a0.z, a0.w, a1.x, a1.y, a1.z, a1.w};
      float s1 = 0.f;
      #pragma unroll
      for (int k = 0; k < 8; ++k) s1 += h[k];
      #pragma unroll
      for (int o = 1; o < 64; o <<= 1) s1 += __shfl_xor(s1, o);
      float m1 = s1 * (1.f / 512.f);
      float s2 = 0.f;
      #pragma unroll
      for (int k = 0; k < 8; ++k) {
        float dv = h[k] - m1;
        s2 += dv * dv;
      }
      #pragma unroll
      for (int o = 1; o < 64; o <<= 1) s2 += __shfl_xor(s2, o);
      float rsd1 = rsqrtf(s2 * (1.f / 512.f) + 1e-5f);

      float hn[8];
      float sh = 0.f, sh2 = 0.f;
      #pragma unroll
      for (int k = 0; k < 8; ++k) {
        float x = (h[k] - m1) * rsd1 * gg[k] + bb[k];
        hn[k] = x; sh += x; sh2 += x * x;
      }
      float* dp = dyn + ((size_t)row * H + tt) * D + lane * 8;
      f32x4 v0 = {hn[0], hn[1], hn[2], hn[3]};
      f32x4 v1 = {hn[4], hn[5], hn[6], hn[7]};
      __builtin_nontemporal_store(v0, (f32x4*)dp);
      __builtin_nontemporal_store(v1, (f32x4*)(dp + 4));

      #pragma unroll
      for (int o = 1; o < 64; o <<= 1) {
        sh += __shfl_xor(sh, o); sh2 += __shfl_xor(sh2, o);
      }
      if (lane == 0) {
        float m2 = (Ssem[row] + sh) * (1.f / 1024.f);
        float vv = (Ssem2[row] + sh2) * (1.f / 1024.f) - m2 * m2;
        float rs2 = rsqrtf(vv + 1e-5f);
        stats_w[row] = make_float4(rsd1, m1 * rsd1, rs2, m2 * rs2);
      }
    }
  }
}

// ---------------------------------------------------------------------------
extern "C" void kernel_launch(void* const* d_in, const int* in_sizes, int n_in,
                              void* d_out, int out_size, void* d_ws, size_t ws_size,
                              hipStream_t stream)
{
  (void)in_sizes; (void)n_in; (void)out_size; (void)ws_size;
  const float* z_dyn = (const float*)d_in[0];
  const float* z_sem = (const float*)d_in[1];
  const float* te_w  = (const float*)d_in[2];
  const float* w_ih  = (const float*)d_in[3];
  const float* w_hh  = (const float*)d_in[4];
  const float* b_ih  = (const float*)d_in[5];
  const float* b_hh  = (const float*)d_in[6];
  const float* ln_g  = (const float*)d_in[7];
  const float* ln_b  = (const float*)d_in[8];
  const float* ln2_g = (const float*)d_in[9];
  const float* ln2_b = (const float*)d_in[10];
  const float* w1    = (const float*)d_in[11];
  const float* b1    = (const float*)d_in[12];
  const float* w2    = (const float*)d_in[13];
  const float* b2    = (const float*)d_in[14];

  char* ws = (char*)d_ws;
  const size_t MB = 1ull << 20;
  u16* hbh[3] = { (u16*)(ws + 0),      (u16*)(ws + 2 * MB),  (u16*)(ws + 4 * MB) };
  u16* hbl[3] = { (u16*)(ws + 6 * MB), (u16*)(ws + 8 * MB),  (u16*)(ws + 10 * MB) };
  float* G0     = (float*)(ws + 12 * MB);            // 12 MB
  float* Psem   = (float*)(ws + 25 * MB);            // 4 MB
  u16*  sem_hi  = (u16*)(ws + 29 * MB);              // 2 MB
  u16*  sem_lo  = (u16*)(ws + 31 * MB);              // 2 MB
  u16*  hid0    = (u16*)(ws + 33 * MB);              // 2 MB
  u16*  hid1    = (u16*)(ws + 35 * MB);              // 2 MB
  u16*  wih_hi  = (u16*)(ws + 37 * MB);              // 1.5 MB
  u16*  wih_lo  = (u16*)(ws + 37 * MB + 1572864);    // 1.5 MB
  u16*  whh_hi  = (u16*)(ws + 40 * MB);              // 1.5 MB
  u16*  whh_lo  = (u16*)(ws + 40 * MB + 1572864);    // 1.5 MB
  u16*  W1s     = (u16*)(ws + 43 * MB);              // 512 KB
  u16*  W1g     = (u16*)(ws + 43 * MB + 524288);     // 512 KB
  u16*  w2bf    = (u16*)(ws + 44 * MB);              // 512 KB
  float* c1     = (float*)(ws + 45 * MB);
  float* c2p    = (float*)(ws + 45 * MB + 16384);
  float* d1     = (float*)(ws + 45 * MB + 32768);
  float* d2     = (float*)(ws + 45 * MB + 49152);
  float* Ssem   = (float*)(ws + 45 * MB + 65536);
  float* Ssem2  = (float*)(ws + 45 * MB + 81920);
  float4* stats0 = (float4*)(ws + 46 * MB);          // 32 KB
  float4* stats1 = (float4*)(ws + 46 * MB + 32768);  // 32 KB
  float* Tg     = (float*)(ws + 47 * MB);            // 192 KB
  float* hf0    = (float*)(ws + 48 * MB);            // 4 MB
  float* hf1    = (float*)(ws + 52 * MB);            // 4 MB

  float* outp = (float*)d_out;
  float* out_dyn  = outp;
  float* out_sems = outp + OUT_HALF;

  // initial state h(-1): hb slot 2 (== (-1) mod 3), hf slot 1 (== (-1) & 1)
  prep_kernel<<<4096, 256, 0, stream>>>(
      z_dyn, z_sem, te_w, w_ih, w_hh, ln_g, ln_b, ln2_g, ln2_b, w1, b1, w2,
      hf1, hbh[2], hbl[2], sem_hi, sem_lo, wih_hi, wih_lo, whh_hi, whh_lo,
      W1s, W1g, w2bf, c1, c2p, d1, d2, Tg);
  rowstats_kernel<<<512, 256, 0, stream>>>(z_sem, Ssem, Ssem2);
  setup_kernel<<<dim3(32, 32), 256, 0, stream>>>(
      sem_hi, sem_lo, wih_hi, wih_lo, W1s, G0, Psem, b_ih);

  for (int t = 0; t <= H + 2; ++t) {
    int s_out  = ((t % 3) + 3) % 3;          // gates write hb slot(t)
    int s_in   = (((t - 1) % 3) + 3) % 3;    // gates read hb slot(t-1)
    int s_ln   = (((t - 2) % 3) + 3) % 3;    // hidGEMM reads hb slot(t-2)
    float* hf_out      = (t & 1) ? hf1 : hf0;
    const float* hf_in = (t & 1) ? hf0 : hf1;   // slot (t-1)&1
    float4* st_w = ((t - 1) & 1) ? stats1 : stats0;
    const float4* st_r = ((t - 2) & 1) ? stats1 : stats0;
    u16* hidw = ((t - 2) & 1) ? hid1 : hid0;
    const u16* hidr = ((t - 3) & 1) ? hid1 : hid0;

    fused_kernel<<<dim3(1152), dim3(256), 0, stream>>>(
        t,
        hbh[s_in], hbl[s_in], hbh[s_out], hbl[s_out],
        hf_in, hf_out,
        whh_hi, whh_lo, G0, Tg, b_hh,
        st_w, out_dyn, ln_g, ln_b, Ssem, Ssem2,
        hbh[s_ln], st_r, W1g, Psem, d1, d2, c1, c2p, hidw,
        hidr, w2bf, z_sem, b2, out_sems);
  }
}